// Round 11
// baseline (2540.411 us; speedup 1.0000x reference)
//
#include <hip/hip_runtime.h>

typedef __attribute__((ext_vector_type(8))) short short8v;
typedef __attribute__((ext_vector_type(4))) float f32x4;

#define NB 1024
#define NS 200
#define ND 512
#define NG 1536
#define NM 204800   // NB*NS
#define NFF 256

#define GRU_P 4     // blocks per group (each owns 128 h-cols)
#define GRU_G 64    // groups (each owns 16 batches)

__device__ __forceinline__ float bf2f(unsigned short u){
  union { unsigned u; float f; } v; v.u = ((unsigned)u) << 16; return v.f;
}
__device__ __forceinline__ unsigned short f2bf(float f){
  union { float f; unsigned u; } v; v.f = f;
  unsigned r = v.u + 0x7fffu + ((v.u >> 16) & 1u);
  return (unsigned short)(r >> 16);
}
__device__ __forceinline__ float sigm(float x){ return 1.f / (1.f + __expf(-x)); }
__device__ __forceinline__ float tanhfast(float x){ return 1.f - 2.f / (1.f + __expf(2.f * x)); }

// ---------------- pack W (N x K, row-major, f32) into MFMA B-frag order ----------------
__global__ void k_prepack(const float* __restrict__ W, unsigned short* __restrict__ out,
                          int ld, int coloff, int ntiles){
  int gid = blockIdx.x * 256 + threadIdx.x;
  if (gid >= ntiles * 1024) return;
  int ntile = gid >> 10; int rem = gid & 1023;
  int kk = rem >> 6; int lane = rem & 63;
  int c = ntile * 16 + (lane & 15);
  int k0 = kk * 32 + (lane >> 4) * 8;
  const float* s = W + (size_t)c * ld + coloff + k0;
  uint4 v;
  v.x = (unsigned)f2bf(s[0]) | ((unsigned)f2bf(s[1]) << 16);
  v.y = (unsigned)f2bf(s[2]) | ((unsigned)f2bf(s[3]) << 16);
  v.z = (unsigned)f2bf(s[4]) | ((unsigned)f2bf(s[5]) << 16);
  v.w = (unsigned)f2bf(s[6]) | ((unsigned)f2bf(s[7]) << 16);
  *(uint4*)(out + (size_t)gid * 8) = v;
}

// ---------------- tvec[b][f] = b_fc[f] + sum_d target[b][d] * W_fc[f][512+d] ----------------
__global__ void k_tvec(const float* __restrict__ target, const float* __restrict__ Wfc,
                       const float* __restrict__ bfc, float* __restrict__ tvec){
  __shared__ float tg[4][ND];
  int bb = blockIdx.x;
  int tid = threadIdx.x;
  for (int idx = tid; idx < 4 * ND; idx += 256){
    int j = idx >> 9, d = idx & 511;
    tg[j][d] = target[(size_t)(bb * 4 + j) * ND + d];
  }
  __syncthreads();
  const float* wrow = Wfc + (size_t)tid * 1024 + 512;
  float a0 = 0, a1 = 0, a2 = 0, a3 = 0;
  for (int d = 0; d < ND; ++d){
    float wv = wrow[d];
    a0 += tg[0][d] * wv; a1 += tg[1][d] * wv; a2 += tg[2][d] * wv; a3 += tg[3][d] * wv;
  }
  float bias = bfc[tid];
  tvec[(size_t)(bb * 4 + 0) * NFF + tid] = a0 + bias;
  tvec[(size_t)(bb * 4 + 1) * NFF + tid] = a1 + bias;
  tvec[(size_t)(bb * 4 + 2) * NFF + tid] = a2 + bias;
  tvec[(size_t)(bb * 4 + 3) * NFF + tid] = a3 + bias;
}

// ---------------- gx = history(f32) @ W_ih^T + bias, output bf16 (NM x 1536) ----------------
// bias folds b_ih (all gates) + b_hh (r,z gates; n-gate b_hh multiplies r in the GRU).
__global__ __launch_bounds__(256) void k_gemm_gx(const float* __restrict__ Af,
                                                 const unsigned short* __restrict__ Bpk,
                                                 const float* __restrict__ bih,
                                                 const float* __restrict__ bhh,
                                                 unsigned short* __restrict__ gx){
  __shared__ unsigned short As[128 * 64];
  int tid = threadIdx.x; int lane = tid & 63; int wid = tid >> 6;
  int wm = wid >> 1, wn = wid & 1;
  int Nb = blockIdx.x, Mb = blockIdx.y;
  const float* Abase = Af + (size_t)Mb * 128 * ND;
  const short8v* Bp = (const short8v*)Bpk;
  f32x4 acc[4][4];
  #pragma unroll
  for (int i = 0; i < 4; ++i)
    #pragma unroll
    for (int j = 0; j < 4; ++j) acc[i][j] = (f32x4){0.f, 0.f, 0.f, 0.f};

  for (int kc = 0; kc < 8; ++kc){
    __syncthreads();
    #pragma unroll
    for (int pass = 0; pass < 4; ++pass){
      int idx = pass * 256 + tid; int r = idx >> 3, ch = idx & 7;
      const float* src = Abase + (size_t)r * ND + kc * 64 + ch * 8;
      float4 f0 = *(const float4*)src;
      float4 f1 = *(const float4*)(src + 4);
      uint4 v;
      v.x = (unsigned)f2bf(f0.x) | ((unsigned)f2bf(f0.y) << 16);
      v.y = (unsigned)f2bf(f0.z) | ((unsigned)f2bf(f0.w) << 16);
      v.z = (unsigned)f2bf(f1.x) | ((unsigned)f2bf(f1.y) << 16);
      v.w = (unsigned)f2bf(f1.z) | ((unsigned)f2bf(f1.w) << 16);
      *(uint4*)&As[r * 64 + ch * 8] = v;
    }
    __syncthreads();
    #pragma unroll
    for (int i = 0; i < 2; ++i){
      short8v a[4];
      #pragma unroll
      for (int mt = 0; mt < 4; ++mt)
        a[mt] = *(const short8v*)&As[(wm * 64 + mt * 16 + (lane & 15)) * 64 + i * 32 + (lane >> 4) * 8];
      #pragma unroll
      for (int nt = 0; nt < 4; ++nt){
        short8v b = Bp[((size_t)(Nb * 8 + wn * 4 + nt) * 16 + (kc * 2 + i)) * 64 + lane];
        #pragma unroll
        for (int mt = 0; mt < 4; ++mt)
          acc[mt][nt] = __builtin_amdgcn_mfma_f32_16x16x32_bf16(a[mt], b, acc[mt][nt], 0, 0, 0);
      }
    }
  }
  #pragma unroll
  for (int mt = 0; mt < 4; ++mt){
    #pragma unroll
    for (int nt = 0; nt < 4; ++nt){
      int gcol = Nb * 128 + wn * 64 + nt * 16 + (lane & 15);
      float bv = bih[gcol] + (gcol < 1024 ? bhh[gcol] : 0.f);
      #pragma unroll
      for (int r = 0; r < 4; ++r){
        int grow = Mb * 128 + wm * 64 + mt * 16 + (lane >> 4) * 4 + r;
        gx[(size_t)grow * NG + gcol] = f2bf(acc[mt][nt][r] + bv);
      }
    }
  }
}

// ---------------- GRU recurrence v10 ----------------
// k_gru7 base (best: 1.22ms) with vmcnt discipline fixed:
//   - gx prefetch at TOP of iteration: drains with the pre-flag vmcnt(0); the poll
//     loop then has ZERO unrelated outstanding vmem (k_gru7 had 12 cold HBM loads
//     draining inside the first poll iteration's vmcnt(0)).
//   - intra-wave LDS transpose (lgkmcnt only, no block barrier before the h-store).
//   - post-poll: reload loads issued first, then gout stores (LDS write waits only reloads).
__global__ __launch_bounds__(512, 1) void k_gru10(const unsigned short* __restrict__ gx,
                                                  const unsigned short* __restrict__ Wpk,
                                                  const float* __restrict__ bhh,
                                                  unsigned short* __restrict__ gout,
                                                  unsigned long long* __restrict__ hx,  // [2][1024*128] u64
                                                  int* __restrict__ flags){             // [GRU_G*32] monotonic
  __shared__ unsigned short hbuf[2][16 * 512];   // [parity][16 k-frags of 1KB]
  __shared__ unsigned short hstg[8][16][20];     // per-wave 16x16 transpose staging (+pad)
  int tid = threadIdx.x; int lane = tid & 63; int nh = tid >> 6;   // wave 0..7
  int bid = blockIdx.x; int g = bid & 63; int s = bid >> 6;        // group, slice
  int colg = lane & 15;
  int rowg = lane >> 4;
  int c_h = s * 128 + nh * 16 + colg;   // this lane's h column
  int b0 = g * 16;                      // group batch base
  int* gfl = flags + g * 32;            // this group's 32 wave-flags

  for (int i = tid; i < 16 * 512; i += 512) hbuf[0][i] = 0;

  // resident W_hh B-fragments: 3 gate tiles x 16 k-frags = 192 regs
  short8v wf[3][16];
  const short8v* Wp = (const short8v*)Wpk;
  #pragma unroll
  for (int gg = 0; gg < 3; ++gg){
    int ntile = gg * 32 + s * 8 + nh;
    #pragma unroll
    for (int kk = 0; kk < 16; ++kk)
      wf[gg][kk] = Wp[((size_t)ntile * 16 + kk) * 64 + lane];
  }
  float bN = bhh[1024 + c_h];   // r,z biases folded into gx
  float hreg[4] = {0.f, 0.f, 0.f, 0.f};

  // preload gx for t=0
  unsigned short cxr[4], cxz[4], cxn[4];
  #pragma unroll
  for (int r = 0; r < 4; ++r){
    const unsigned short* gp = gx + ((size_t)(b0 + rowg * 4 + r) * NS + 0) * NG;
    cxr[r] = gp[c_h]; cxz[r] = gp[512 + c_h]; cxn[r] = gp[1024 + c_h];
  }
  __syncthreads();

  #pragma unroll 1
  for (int t = 0; t < NS; ++t){
    int par = t & 1;
    const unsigned short* hr = hbuf[par];
    // TOP-of-iteration gx prefetch for t+1: HBM latency hides under MFMA phase,
    // fully drained by the pre-flag vmcnt(0) -> poll loop sees clean vmcnt.
    unsigned short nxr[4], nxz[4], nxn[4];
    if (t + 1 < NS){
      #pragma unroll
      for (int r = 0; r < 4; ++r){
        const unsigned short* gp = gx + ((size_t)(b0 + rowg * 4 + r) * NS + (t + 1)) * NG;
        nxr[r] = gp[c_h]; nxz[r] = gp[512 + c_h]; nxn[r] = gp[1024 + c_h];
      }
    }
    // gh = h @ Whh_slice^T
    f32x4 acc0 = (f32x4){0.f,0.f,0.f,0.f}, acc1 = acc0, acc2 = acc0;
    #pragma unroll
    for (int kc = 0; kc < 16; ++kc){
      short8v a = *(const short8v*)&hr[kc * 512 + lane * 8];
      acc0 = __builtin_amdgcn_mfma_f32_16x16x32_bf16(a, wf[0][kc], acc0, 0, 0, 0);
      acc1 = __builtin_amdgcn_mfma_f32_16x16x32_bf16(a, wf[1][kc], acc1, 0, 0, 0);
      acc2 = __builtin_amdgcn_mfma_f32_16x16x32_bf16(a, wf[2][kc], acc2, 0, 0, 0);
    }
    // activations; h kept f32 in regs
    unsigned short hnew[4];
    #pragma unroll
    for (int r = 0; r < 4; ++r){
      float rr = sigm(bf2f(cxr[r]) + acc0[r]);
      float zz = sigm(bf2f(cxz[r]) + acc1[r]);
      float nn = tanhfast(bf2f(cxn[r]) + rr * (acc2[r] + bN));
      float h = nn + zz * (hreg[r] - nn);
      hreg[r] = h;
      hnew[r] = f2bf(h);
    }

    if (t + 1 < NS){
      unsigned long long* hxp = hx + (size_t)par * (1024 * 128);
      // intra-wave 16x16 transpose (no block barrier)
      #pragma unroll
      for (int r = 0; r < 4; ++r) hstg[nh][rowg * 4 + r][colg] = hnew[r];
      asm volatile("s_waitcnt lgkmcnt(0)" ::: "memory");
      // ONE 8B coherent store per lane: batch=lane&15, col-quad=lane>>4
      {
        unsigned long long v8 = *(const unsigned long long*)&hstg[nh][lane & 15][(lane >> 4) * 4];
        __hip_atomic_store(&hxp[(size_t)(b0 + (lane & 15)) * 128 + s * 32 + nh * 4 + (lane >> 4)], v8,
                           __ATOMIC_RELAXED, __HIP_MEMORY_SCOPE_AGENT);
      }
      asm volatile("s_waitcnt vmcnt(0)" ::: "memory");   // drains h-store (+ finished nx loads)
      if (lane == 0)
        __hip_atomic_store(&gfl[s * 8 + nh], t + 1, __ATOMIC_RELAXED, __HIP_MEMORY_SCOPE_AGENT);
      // all-wave poll of the 32 wave-flags; NO unrelated vmem outstanding
      {
        int need = t + 1; int fv;
        do {
          fv = (lane < 32) ? __hip_atomic_load(&gfl[lane], __ATOMIC_RELAXED, __HIP_MEMORY_SCOPE_AGENT) : need;
        } while (!__all(fv >= need));
      }
      asm volatile("" ::: "memory");
      // reload loads first (latency-critical), then gout stores
      size_t base1 = (size_t)(b0 + (lane & 15)) * 128 + nh * 8 + (lane >> 4) * 2;
      unsigned long long u0 = __hip_atomic_load(&hxp[base1],      __ATOMIC_RELAXED, __HIP_MEMORY_SCOPE_AGENT);
      unsigned long long u1 = __hip_atomic_load(&hxp[base1 + 1],  __ATOMIC_RELAXED, __HIP_MEMORY_SCOPE_AGENT);
      unsigned long long u2 = __hip_atomic_load(&hxp[base1 + 64], __ATOMIC_RELAXED, __HIP_MEMORY_SCOPE_AGENT);
      unsigned long long u3 = __hip_atomic_load(&hxp[base1 + 65], __ATOMIC_RELAXED, __HIP_MEMORY_SCOPE_AGENT);
      #pragma unroll
      for (int r = 0; r < 4; ++r)
        gout[((size_t)(b0 + rowg * 4 + r) * NS + t) * ND + c_h] = hnew[r];
      unsigned short* hw = hbuf[par ^ 1];
      { unsigned long long tmp[2] = {u0, u1}; *(uint4*)&hw[nh * 512 + lane * 8] = *(const uint4*)tmp; }
      { unsigned long long tmp[2] = {u2, u3}; *(uint4*)&hw[(nh + 8) * 512 + lane * 8] = *(const uint4*)tmp; }
      __syncthreads();   // LDS ready; restores symmetric hb-union across the group
    } else {
      #pragma unroll
      for (int r = 0; r < 4; ++r)
        gout[((size_t)(b0 + rowg * 4 + r) * NS + t) * ND + c_h] = hnew[r];
    }
    #pragma unroll
    for (int r = 0; r < 4; ++r){ cxr[r] = nxr[r]; cxz[r] = nxz[r]; cxn[r] = nxn[r]; }
  }
}

// ---------------- pre/GELU/scores fused GEMM: (NM x 512) @ Wg^T (256) ----------------
__global__ __launch_bounds__(512) void k_gemm_s4(const unsigned short* __restrict__ A,
                                                 const unsigned short* __restrict__ Bpk,
                                                 const float* __restrict__ tvec,
                                                 const float* __restrict__ Wsc,
                                                 const float* __restrict__ bsc,
                                                 float* __restrict__ scores){
  __shared__ unsigned short As[128 * 64];
  __shared__ float spart[4][128];
  int tid = threadIdx.x; int lane = tid & 63; int wid = tid >> 6;
  int wm = wid >> 2, wn = wid & 3;
  int Mb = blockIdx.x;
  const unsigned short* Abase = A + (size_t)Mb * 128 * ND;
  const short8v* Bp = (const short8v*)Bpk;
  f32x4 acc[4][4];
  #pragma unroll
  for (int i = 0; i < 4; ++i)
    #pragma unroll
    for (int j = 0; j < 4; ++j) acc[i][j] = (f32x4){0.f, 0.f, 0.f, 0.f};

  for (int kc = 0; kc < 8; ++kc){
    __syncthreads();
    #pragma unroll
    for (int pass = 0; pass < 2; ++pass){
      int idx = pass * 512 + tid; int r = idx >> 3, ch = idx & 7;
      uint4 v = *(const uint4*)(Abase + (size_t)r * ND + kc * 64 + ch * 8);
      *(uint4*)&As[r * 64 + ch * 8] = v;
    }
    __syncthreads();
    #pragma unroll
    for (int i = 0; i < 2; ++i){
      short8v a[4];
      #pragma unroll
      for (int mt = 0; mt < 4; ++mt)
        a[mt] = *(const short8v*)&As[(wm * 64 + mt * 16 + (lane & 15)) * 64 + i * 32 + (lane >> 4) * 8];
      #pragma unroll
      for (int nt = 0; nt < 4; ++nt){
        short8v b = Bp[((size_t)(wn * 4 + nt) * 16 + (kc * 2 + i)) * 64 + lane];
        #pragma unroll
        for (int mt = 0; mt < 4; ++mt)
          acc[mt][nt] = __builtin_amdgcn_mfma_f32_16x16x32_bf16(a[mt], b, acc[mt][nt], 0, 0, 0);
      }
    }
  }
  #pragma unroll
  for (int mt = 0; mt < 4; ++mt){
    #pragma unroll
    for (int r = 0; r < 4; ++r){
      int rowl = wm * 64 + mt * 16 + (lane >> 4) * 4 + r;
      unsigned grow = (unsigned)(Mb * 128 + rowl);
      unsigned bidx = grow / 200u;
      float rowsum = 0.f;
      #pragma unroll
      for (int nt = 0; nt < 4; ++nt){
        int gcol = wn * 64 + nt * 16 + (lane & 15);
        float pre = acc[mt][nt][r] + tvec[(size_t)bidx * NFF + gcol];
        float g = 0.5f * pre * (1.f + erff(pre * 0.70710678118654752f));
        rowsum += g * Wsc[gcol];
      }
      rowsum += __shfl_xor(rowsum, 1, 64);
      rowsum += __shfl_xor(rowsum, 2, 64);
      rowsum += __shfl_xor(rowsum, 4, 64);
      rowsum += __shfl_xor(rowsum, 8, 64);
      if ((lane & 15) == 0) spart[wn][rowl] = rowsum;
    }
  }
  __syncthreads();
  if (tid < 128){
    float s = spart[0][tid] + spart[1][tid] + spart[2][tid] + spart[3][tid] + bsc[0];
    scores[(size_t)Mb * 128 + tid] = s;
  }
}

// ---------------- softmax over S + weighted pool + concat output ----------------
__global__ void k_out(const float* __restrict__ scores, const unsigned short* __restrict__ gout,
                      const float* __restrict__ target, float* __restrict__ out){
  int b = blockIdx.x; int tid = threadIdx.x;
  __shared__ float sw[NS];
  __shared__ float red[4];
  float v = (tid < NS) ? scores[(size_t)b * NS + tid] : -3.0e38f;
  float m = v;
  #pragma unroll
  for (int off = 32; off >= 1; off >>= 1) m = fmaxf(m, __shfl_xor(m, off, 64));
  if ((tid & 63) == 0) red[tid >> 6] = m;
  __syncthreads();
  m = fmaxf(fmaxf(red[0], red[1]), fmaxf(red[2], red[3]));
  float e = (tid < NS) ? __expf(v - m) : 0.f;
  if (tid < NS) sw[tid] = e;
  float su = e;
  #pragma unroll
  for (int off = 32; off >= 1; off >>= 1) su += __shfl_xor(su, off, 64);
  __syncthreads();
  if ((tid & 63) == 0) red[tid >> 6] = su;
  __syncthreads();
  float inv = 1.f / (red[0] + red[1] + red[2] + red[3]);
  int d0 = tid * 2;
  float a0 = 0.f, a1 = 0.f;
  const unsigned short* gbase = gout + (size_t)b * NS * ND + d0;
  for (int s = 0; s < NS; ++s){
    unsigned u = *(const unsigned*)(gbase + (size_t)s * ND);
    float wgt = sw[s];
    a0 += wgt * bf2f((unsigned short)(u & 0xffffu));
    a1 += wgt * bf2f((unsigned short)(u >> 16));
  }
  out[(size_t)b * 1024 + d0] = a0 * inv;
  out[(size_t)b * 1024 + d0 + 1] = a1 * inv;
  float2 tv = *(const float2*)(target + (size_t)b * ND + d0);
  out[(size_t)b * 1024 + 512 + d0] = tv.x;
  out[(size_t)b * 1024 + 512 + d0 + 1] = tv.y;
}

extern "C" void kernel_launch(void* const* d_in, const int* in_sizes, int n_in,
                              void* d_out, int out_size, void* d_ws, size_t ws_size,
                              hipStream_t stream) {
  const float* target  = (const float*)d_in[0];
  const float* history = (const float*)d_in[1];
  const float* W_ih    = (const float*)d_in[2];
  const float* W_hh    = (const float*)d_in[3];
  const float* b_ih    = (const float*)d_in[4];
  const float* b_hh    = (const float*)d_in[5];
  const float* W_fc    = (const float*)d_in[6];
  const float* b_fc    = (const float*)d_in[7];
  const float* W_sc    = (const float*)d_in[8];
  const float* b_sc    = (const float*)d_in[9];

  char* ws = (char*)d_ws;
  size_t off = 0;
  unsigned short* gx     = (unsigned short*)(ws + off); off += 629145600ull;  // NM*1536 bf16
  unsigned short* gout   = (unsigned short*)(ws + off); off += 209715200ull;  // NM*512 bf16
  unsigned short* wih_pk = (unsigned short*)(ws + off); off += 1572864ull;
  unsigned short* whh_pk = (unsigned short*)(ws + off); off += 1572864ull;
  unsigned short* wg_pk  = (unsigned short*)(ws + off); off += 262144ull;
  float*          tvec   = (float*)(ws + off);          off += 1048576ull;
  float*          scores = (float*)(ws + off);          off += 819200ull;
  unsigned long long* hx = (unsigned long long*)(ws + off); off += 2097152ull; // [2][1024*128] u64
  int*            flags  = (int*)(ws + off);             off += 8192ull;        // [64*32] monotonic
  if (ws_size < off) return;
  float* outp = (float*)d_out;

  (void)hipMemsetAsync(flags, 0, GRU_G * 32 * sizeof(int), stream);
  k_prepack<<<384, 256, 0, stream>>>(W_ih, wih_pk, 512, 0, 96);
  k_prepack<<<384, 256, 0, stream>>>(W_hh, whh_pk, 512, 0, 96);
  k_prepack<<<64, 256, 0, stream>>>(W_fc, wg_pk, 1024, 0, 16);
  k_tvec<<<256, 256, 0, stream>>>(target, W_fc, b_fc, tvec);
  k_gemm_gx<<<dim3(12, 1600), 256, 0, stream>>>(history, wih_pk, b_ih, b_hh, gx);
  k_gru10<<<256, 512, 0, stream>>>(gx, whh_pk, b_hh, gout, hx, flags);
  k_gemm_s4<<<1600, 512, 0, stream>>>(gout, wg_pk, tvec, W_sc, b_sc, scores);
  k_out<<<1024, 256, 0, stream>>>(scores, gout, target, outp);
}

// Round 12
// 2292.768 us; speedup vs baseline: 1.1080x; 1.1080x over previous
//
#include <hip/hip_runtime.h>

typedef __attribute__((ext_vector_type(8))) short short8v;
typedef __attribute__((ext_vector_type(4))) float f32x4;

#define NB 1024
#define NS 200
#define ND 512
#define NG 1536
#define NM 204800   // NB*NS
#define NFF 256

#define GRU_P 4     // blocks per group (each owns 128 h-cols)
#define GRU_G 64    // groups (each owns 16 batches)

__device__ __forceinline__ float bf2f(unsigned short u){
  union { unsigned u; float f; } v; v.u = ((unsigned)u) << 16; return v.f;
}
__device__ __forceinline__ unsigned short f2bf(float f){
  union { float f; unsigned u; } v; v.f = f;
  unsigned r = v.u + 0x7fffu + ((v.u >> 16) & 1u);
  return (unsigned short)(r >> 16);
}
__device__ __forceinline__ float sigm(float x){ return 1.f / (1.f + __expf(-x)); }
__device__ __forceinline__ float tanhfast(float x){ return 1.f - 2.f / (1.f + __expf(2.f * x)); }

// ---------------- pack W (N x K, row-major, f32) into MFMA B-frag order ----------------
__global__ void k_prepack(const float* __restrict__ W, unsigned short* __restrict__ out,
                          int ld, int coloff, int ntiles){
  int gid = blockIdx.x * 256 + threadIdx.x;
  if (gid >= ntiles * 1024) return;
  int ntile = gid >> 10; int rem = gid & 1023;
  int kk = rem >> 6; int lane = rem & 63;
  int c = ntile * 16 + (lane & 15);
  int k0 = kk * 32 + (lane >> 4) * 8;
  const float* s = W + (size_t)c * ld + coloff + k0;
  uint4 v;
  v.x = (unsigned)f2bf(s[0]) | ((unsigned)f2bf(s[1]) << 16);
  v.y = (unsigned)f2bf(s[2]) | ((unsigned)f2bf(s[3]) << 16);
  v.z = (unsigned)f2bf(s[4]) | ((unsigned)f2bf(s[5]) << 16);
  v.w = (unsigned)f2bf(s[6]) | ((unsigned)f2bf(s[7]) << 16);
  *(uint4*)(out + (size_t)gid * 8) = v;
}

// ---------------- tvec[b][f] = b_fc[f] + sum_d target[b][d] * W_fc[f][512+d] ----------------
__global__ void k_tvec(const float* __restrict__ target, const float* __restrict__ Wfc,
                       const float* __restrict__ bfc, float* __restrict__ tvec){
  __shared__ float tg[4][ND];
  int bb = blockIdx.x;
  int tid = threadIdx.x;
  for (int idx = tid; idx < 4 * ND; idx += 256){
    int j = idx >> 9, d = idx & 511;
    tg[j][d] = target[(size_t)(bb * 4 + j) * ND + d];
  }
  __syncthreads();
  const float* wrow = Wfc + (size_t)tid * 1024 + 512;
  float a0 = 0, a1 = 0, a2 = 0, a3 = 0;
  for (int d = 0; d < ND; ++d){
    float wv = wrow[d];
    a0 += tg[0][d] * wv; a1 += tg[1][d] * wv; a2 += tg[2][d] * wv; a3 += tg[3][d] * wv;
  }
  float bias = bfc[tid];
  tvec[(size_t)(bb * 4 + 0) * NFF + tid] = a0 + bias;
  tvec[(size_t)(bb * 4 + 1) * NFF + tid] = a1 + bias;
  tvec[(size_t)(bb * 4 + 2) * NFF + tid] = a2 + bias;
  tvec[(size_t)(bb * 4 + 3) * NFF + tid] = a3 + bias;
}

// ---------------- gx = history(f32) @ W_ih^T + bias, output bf16 (NM x 1536) ----------------
// bias folds b_ih (all gates) + b_hh (r,z gates; n-gate b_hh multiplies r in the GRU).
__global__ __launch_bounds__(256) void k_gemm_gx(const float* __restrict__ Af,
                                                 const unsigned short* __restrict__ Bpk,
                                                 const float* __restrict__ bih,
                                                 const float* __restrict__ bhh,
                                                 unsigned short* __restrict__ gx){
  __shared__ unsigned short As[128 * 64];
  int tid = threadIdx.x; int lane = tid & 63; int wid = tid >> 6;
  int wm = wid >> 1, wn = wid & 1;
  int Nb = blockIdx.x, Mb = blockIdx.y;
  const float* Abase = Af + (size_t)Mb * 128 * ND;
  const short8v* Bp = (const short8v*)Bpk;
  f32x4 acc[4][4];
  #pragma unroll
  for (int i = 0; i < 4; ++i)
    #pragma unroll
    for (int j = 0; j < 4; ++j) acc[i][j] = (f32x4){0.f, 0.f, 0.f, 0.f};

  for (int kc = 0; kc < 8; ++kc){
    __syncthreads();
    #pragma unroll
    for (int pass = 0; pass < 4; ++pass){
      int idx = pass * 256 + tid; int r = idx >> 3, ch = idx & 7;
      const float* src = Abase + (size_t)r * ND + kc * 64 + ch * 8;
      float4 f0 = *(const float4*)src;
      float4 f1 = *(const float4*)(src + 4);
      uint4 v;
      v.x = (unsigned)f2bf(f0.x) | ((unsigned)f2bf(f0.y) << 16);
      v.y = (unsigned)f2bf(f0.z) | ((unsigned)f2bf(f0.w) << 16);
      v.z = (unsigned)f2bf(f1.x) | ((unsigned)f2bf(f1.y) << 16);
      v.w = (unsigned)f2bf(f1.z) | ((unsigned)f2bf(f1.w) << 16);
      *(uint4*)&As[r * 64 + ch * 8] = v;
    }
    __syncthreads();
    #pragma unroll
    for (int i = 0; i < 2; ++i){
      short8v a[4];
      #pragma unroll
      for (int mt = 0; mt < 4; ++mt)
        a[mt] = *(const short8v*)&As[(wm * 64 + mt * 16 + (lane & 15)) * 64 + i * 32 + (lane >> 4) * 8];
      #pragma unroll
      for (int nt = 0; nt < 4; ++nt){
        short8v b = Bp[((size_t)(Nb * 8 + wn * 4 + nt) * 16 + (kc * 2 + i)) * 64 + lane];
        #pragma unroll
        for (int mt = 0; mt < 4; ++mt)
          acc[mt][nt] = __builtin_amdgcn_mfma_f32_16x16x32_bf16(a[mt], b, acc[mt][nt], 0, 0, 0);
      }
    }
  }
  #pragma unroll
  for (int mt = 0; mt < 4; ++mt){
    #pragma unroll
    for (int nt = 0; nt < 4; ++nt){
      int gcol = Nb * 128 + wn * 64 + nt * 16 + (lane & 15);
      float bv = bih[gcol] + (gcol < 1024 ? bhh[gcol] : 0.f);
      #pragma unroll
      for (int r = 0; r < 4; ++r){
        int grow = Mb * 128 + wm * 64 + mt * 16 + (lane >> 4) * 4 + r;
        gx[(size_t)grow * NG + gcol] = f2bf(acc[mt][nt][r] + bv);
      }
    }
  }
}

// ---------------- GRU recurrence v11 = v7 (best, 1.22ms) + s_sleep poll backoff ----------------
// v7 structure byte-for-byte: block-barrier transpose staging -> coalesced ONE-8B-store
// per thread -> per-wave vmcnt drain -> per-wave monotonic flag -> gout + gx prefetch in
// poll shadow -> all-wave 32-flag poll -> reload -> barrier.
// NEW: s_sleep(2) between failed poll iterations (poll CP traffic / ~3-4; tests the
// coherence-point-congestion theory with zero structural change).
__global__ __launch_bounds__(512, 1) void k_gru11(const unsigned short* __restrict__ gx,
                                                  const unsigned short* __restrict__ Wpk,
                                                  const float* __restrict__ bhh,
                                                  unsigned short* __restrict__ gout,
                                                  unsigned long long* __restrict__ hx,  // [2][1024*128] u64
                                                  int* __restrict__ flags){             // [GRU_G*32] monotonic
  __shared__ unsigned short hbuf[2][16 * 512];   // [parity][16 k-frags of 1KB]
  __shared__ unsigned short hstg[16][136];       // block h-slice transpose staging (+pad)
  int tid = threadIdx.x; int lane = tid & 63; int nh = tid >> 6;   // wave 0..7
  int bid = blockIdx.x; int g = bid & 63; int s = bid >> 6;        // group, slice
  int colg = lane & 15;
  int rowg = lane >> 4;
  int c_h = s * 128 + nh * 16 + colg;   // this lane's h column
  int b0 = g * 16;                      // group batch base
  int* gfl = flags + g * 32;            // this group's 32 wave-flags

  for (int i = tid; i < 16 * 512; i += 512) hbuf[0][i] = 0;

  // resident W_hh B-fragments: 3 gate tiles x 16 k-frags = 192 regs
  short8v wf[3][16];
  const short8v* Wp = (const short8v*)Wpk;
  #pragma unroll
  for (int gg = 0; gg < 3; ++gg){
    int ntile = gg * 32 + s * 8 + nh;
    #pragma unroll
    for (int kk = 0; kk < 16; ++kk)
      wf[gg][kk] = Wp[((size_t)ntile * 16 + kk) * 64 + lane];
  }
  float bN = bhh[1024 + c_h];   // r,z biases folded into gx
  float hreg[4] = {0.f, 0.f, 0.f, 0.f};

  // writer mapping: thread -> one u64 (4 cols) of this block's h-slice
  int wbat = tid >> 5;            // 0..15
  int wc4  = tid & 31;            // 0..31 (4-col chunk within 128)

  // preload gx for t=0
  unsigned short cxr[4], cxz[4], cxn[4];
  #pragma unroll
  for (int r = 0; r < 4; ++r){
    const unsigned short* gp = gx + ((size_t)(b0 + rowg * 4 + r) * NS + 0) * NG;
    cxr[r] = gp[c_h]; cxz[r] = gp[512 + c_h]; cxn[r] = gp[1024 + c_h];
  }
  __syncthreads();

  #pragma unroll 1
  for (int t = 0; t < NS; ++t){
    int par = t & 1;
    const unsigned short* hr = hbuf[par];
    // gh = h @ Whh_slice^T
    f32x4 acc0 = (f32x4){0.f,0.f,0.f,0.f}, acc1 = acc0, acc2 = acc0;
    #pragma unroll
    for (int kc = 0; kc < 16; ++kc){
      short8v a = *(const short8v*)&hr[kc * 512 + lane * 8];
      acc0 = __builtin_amdgcn_mfma_f32_16x16x32_bf16(a, wf[0][kc], acc0, 0, 0, 0);
      acc1 = __builtin_amdgcn_mfma_f32_16x16x32_bf16(a, wf[1][kc], acc1, 0, 0, 0);
      acc2 = __builtin_amdgcn_mfma_f32_16x16x32_bf16(a, wf[2][kc], acc2, 0, 0, 0);
    }
    // activations; h kept f32 in regs (r,z biases pre-folded into gx)
    unsigned short hnew[4];
    #pragma unroll
    for (int r = 0; r < 4; ++r){
      float rr = sigm(bf2f(cxr[r]) + acc0[r]);
      float zz = sigm(bf2f(cxz[r]) + acc1[r]);
      float nn = tanhfast(bf2f(cxn[r]) + rr * (acc2[r] + bN));
      float h = nn + zz * (hreg[r] - nn);
      hreg[r] = h;
      hnew[r] = f2bf(h);
    }

    if (t + 1 < NS){
      unsigned long long* hxp = hx + (size_t)par * (1024 * 128);
      // transpose-stage this block's 16x128 h-slice in LDS
      #pragma unroll
      for (int r = 0; r < 4; ++r) hstg[rowg * 4 + r][nh * 16 + colg] = hnew[r];
      __syncthreads();   // Bstg: slice staged
      // ONE coalesced 8B coherent store per thread
      {
        unsigned long long v8 = *(const unsigned long long*)&hstg[wbat][wc4 * 4];
        __hip_atomic_store(&hxp[(size_t)(b0 + wbat) * 128 + s * 32 + wc4], v8,
                           __ATOMIC_RELAXED, __HIP_MEMORY_SCOPE_AGENT);
      }
      // per-wave drain of the store, then per-wave flag (publish ASAP)
      asm volatile("s_waitcnt vmcnt(0)" ::: "memory");
      if (lane == 0)
        __hip_atomic_store(&gfl[s * 8 + nh], t + 1, __ATOMIC_RELAXED, __HIP_MEMORY_SCOPE_AGENT);
      // off the publish path: gout stores + gx prefetch (fly during poll)
      #pragma unroll
      for (int r = 0; r < 4; ++r)
        gout[((size_t)(b0 + rowg * 4 + r) * NS + t) * ND + c_h] = hnew[r];
      #pragma unroll
      for (int r = 0; r < 4; ++r){
        const unsigned short* gp = gx + ((size_t)(b0 + rowg * 4 + r) * NS + (t + 1)) * NG;
        cxr[r] = gp[c_h]; cxz[r] = gp[512 + c_h]; cxn[r] = gp[1024 + c_h];
      }
      // all-wave poll of the 32 wave-flags, with s_sleep backoff
      {
        int need = t + 1; int fv;
        for (;;){
          fv = (lane < 32) ? __hip_atomic_load(&gfl[lane], __ATOMIC_RELAXED, __HIP_MEMORY_SCOPE_AGENT) : need;
          if (__all(fv >= need)) break;
          __builtin_amdgcn_s_sleep(2);
        }
      }
      asm volatile("" ::: "memory");
      // reload full h_t into other-parity LDS in MFMA A-frag layout
      unsigned short* hw = hbuf[par ^ 1];
      #pragma unroll
      for (int q = 0; q < 2; ++q){
        int kc = q * 8 + nh;
        size_t base = (size_t)(b0 + (lane & 15)) * 128 + kc * 8 + (lane >> 4) * 2;
        unsigned long long u0 = __hip_atomic_load(&hxp[base],     __ATOMIC_RELAXED, __HIP_MEMORY_SCOPE_AGENT);
        unsigned long long u1 = __hip_atomic_load(&hxp[base + 1], __ATOMIC_RELAXED, __HIP_MEMORY_SCOPE_AGENT);
        unsigned long long tmp[2] = {u0, u1};
        *(uint4*)&hw[kc * 512 + lane * 8] = *(const uint4*)tmp;
      }
      __syncthreads();   // LDS h ready for next step
    } else {
      #pragma unroll
      for (int r = 0; r < 4; ++r)
        gout[((size_t)(b0 + rowg * 4 + r) * NS + t) * ND + c_h] = hnew[r];
    }
  }
}

// ---------------- pre/GELU/scores fused GEMM: (NM x 512) @ Wg^T (256) ----------------
__global__ __launch_bounds__(512) void k_gemm_s4(const unsigned short* __restrict__ A,
                                                 const unsigned short* __restrict__ Bpk,
                                                 const float* __restrict__ tvec,
                                                 const float* __restrict__ Wsc,
                                                 const float* __restrict__ bsc,
                                                 float* __restrict__ scores){
  __shared__ unsigned short As[128 * 64];
  __shared__ float spart[4][128];
  int tid = threadIdx.x; int lane = tid & 63; int wid = tid >> 6;
  int wm = wid >> 2, wn = wid & 3;
  int Mb = blockIdx.x;
  const unsigned short* Abase = A + (size_t)Mb * 128 * ND;
  const short8v* Bp = (const short8v*)Bpk;
  f32x4 acc[4][4];
  #pragma unroll
  for (int i = 0; i < 4; ++i)
    #pragma unroll
    for (int j = 0; j < 4; ++j) acc[i][j] = (f32x4){0.f, 0.f, 0.f, 0.f};

  for (int kc = 0; kc < 8; ++kc){
    __syncthreads();
    #pragma unroll
    for (int pass = 0; pass < 2; ++pass){
      int idx = pass * 512 + tid; int r = idx >> 3, ch = idx & 7;
      uint4 v = *(const uint4*)(Abase + (size_t)r * ND + kc * 64 + ch * 8);
      *(uint4*)&As[r * 64 + ch * 8] = v;
    }
    __syncthreads();
    #pragma unroll
    for (int i = 0; i < 2; ++i){
      short8v a[4];
      #pragma unroll
      for (int mt = 0; mt < 4; ++mt)
        a[mt] = *(const short8v*)&As[(wm * 64 + mt * 16 + (lane & 15)) * 64 + i * 32 + (lane >> 4) * 8];
      #pragma unroll
      for (int nt = 0; nt < 4; ++nt){
        short8v b = Bp[((size_t)(wn * 4 + nt) * 16 + (kc * 2 + i)) * 64 + lane];
        #pragma unroll
        for (int mt = 0; mt < 4; ++mt)
          acc[mt][nt] = __builtin_amdgcn_mfma_f32_16x16x32_bf16(a[mt], b, acc[mt][nt], 0, 0, 0);
      }
    }
  }
  #pragma unroll
  for (int mt = 0; mt < 4; ++mt){
    #pragma unroll
    for (int r = 0; r < 4; ++r){
      int rowl = wm * 64 + mt * 16 + (lane >> 4) * 4 + r;
      unsigned grow = (unsigned)(Mb * 128 + rowl);
      unsigned bidx = grow / 200u;
      float rowsum = 0.f;
      #pragma unroll
      for (int nt = 0; nt < 4; ++nt){
        int gcol = wn * 64 + nt * 16 + (lane & 15);
        float pre = acc[mt][nt][r] + tvec[(size_t)bidx * NFF + gcol];
        float g = 0.5f * pre * (1.f + erff(pre * 0.70710678118654752f));
        rowsum += g * Wsc[gcol];
      }
      rowsum += __shfl_xor(rowsum, 1, 64);
      rowsum += __shfl_xor(rowsum, 2, 64);
      rowsum += __shfl_xor(rowsum, 4, 64);
      rowsum += __shfl_xor(rowsum, 8, 64);
      if ((lane & 15) == 0) spart[wn][rowl] = rowsum;
    }
  }
  __syncthreads();
  if (tid < 128){
    float s = spart[0][tid] + spart[1][tid] + spart[2][tid] + spart[3][tid] + bsc[0];
    scores[(size_t)Mb * 128 + tid] = s;
  }
}

// ---------------- softmax over S + weighted pool + concat output ----------------
__global__ void k_out(const float* __restrict__ scores, const unsigned short* __restrict__ gout,
                      const float* __restrict__ target, float* __restrict__ out){
  int b = blockIdx.x; int tid = threadIdx.x;
  __shared__ float sw[NS];
  __shared__ float red[4];
  float v = (tid < NS) ? scores[(size_t)b * NS + tid] : -3.0e38f;
  float m = v;
  #pragma unroll
  for (int off = 32; off >= 1; off >>= 1) m = fmaxf(m, __shfl_xor(m, off, 64));
  if ((tid & 63) == 0) red[tid >> 6] = m;
  __syncthreads();
  m = fmaxf(fmaxf(red[0], red[1]), fmaxf(red[2], red[3]));
  float e = (tid < NS) ? __expf(v - m) : 0.f;
  if (tid < NS) sw[tid] = e;
  float su = e;
  #pragma unroll
  for (int off = 32; off >= 1; off >>= 1) su += __shfl_xor(su, off, 64);
  __syncthreads();
  if ((tid & 63) == 0) red[tid >> 6] = su;
  __syncthreads();
  float inv = 1.f / (red[0] + red[1] + red[2] + red[3]);
  int d0 = tid * 2;
  float a0 = 0.f, a1 = 0.f;
  const unsigned short* gbase = gout + (size_t)b * NS * ND + d0;
  for (int s = 0; s < NS; ++s){
    unsigned u = *(const unsigned*)(gbase + (size_t)s * ND);
    float wgt = sw[s];
    a0 += wgt * bf2f((unsigned short)(u & 0xffffu));
    a1 += wgt * bf2f((unsigned short)(u >> 16));
  }
  out[(size_t)b * 1024 + d0] = a0 * inv;
  out[(size_t)b * 1024 + d0 + 1] = a1 * inv;
  float2 tv = *(const float2*)(target + (size_t)b * ND + d0);
  out[(size_t)b * 1024 + 512 + d0] = tv.x;
  out[(size_t)b * 1024 + 512 + d0 + 1] = tv.y;
}

extern "C" void kernel_launch(void* const* d_in, const int* in_sizes, int n_in,
                              void* d_out, int out_size, void* d_ws, size_t ws_size,
                              hipStream_t stream) {
  const float* target  = (const float*)d_in[0];
  const float* history = (const float*)d_in[1];
  const float* W_ih    = (const float*)d_in[2];
  const float* W_hh    = (const float*)d_in[3];
  const float* b_ih    = (const float*)d_in[4];
  const float* b_hh    = (const float*)d_in[5];
  const float* W_fc    = (const float*)d_in[6];
  const float* b_fc    = (const float*)d_in[7];
  const float* W_sc    = (const float*)d_in[8];
  const float* b_sc    = (const float*)d_in[9];

  char* ws = (char*)d_ws;
  size_t off = 0;
  unsigned short* gx     = (unsigned short*)(ws + off); off += 629145600ull;  // NM*1536 bf16
  unsigned short* gout   = (unsigned short*)(ws + off); off += 209715200ull;  // NM*512 bf16
  unsigned short* wih_pk = (unsigned short*)(ws + off); off += 1572864ull;
  unsigned short* whh_pk = (unsigned short*)(ws + off); off += 1572864ull;
  unsigned short* wg_pk  = (unsigned short*)(ws + off); off += 262144ull;
  float*          tvec   = (float*)(ws + off);          off += 1048576ull;
  float*          scores = (float*)(ws + off);          off += 819200ull;
  unsigned long long* hx = (unsigned long long*)(ws + off); off += 2097152ull; // [2][1024*128] u64
  int*            flags  = (int*)(ws + off);             off += 8192ull;        // [64*32] monotonic
  if (ws_size < off) return;
  float* outp = (float*)d_out;

  (void)hipMemsetAsync(flags, 0, GRU_G * 32 * sizeof(int), stream);
  k_prepack<<<384, 256, 0, stream>>>(W_ih, wih_pk, 512, 0, 96);
  k_prepack<<<384, 256, 0, stream>>>(W_hh, whh_pk, 512, 0, 96);
  k_prepack<<<64, 256, 0, stream>>>(W_fc, wg_pk, 1024, 0, 16);
  k_tvec<<<256, 256, 0, stream>>>(target, W_fc, b_fc, tvec);
  k_gemm_gx<<<dim3(12, 1600), 256, 0, stream>>>(history, wih_pk, b_ih, b_hh, gx);
  k_gru11<<<256, 512, 0, stream>>>(gx, whh_pk, b_hh, gout, hx, flags);
  k_gemm_s4<<<1600, 512, 0, stream>>>(gout, wg_pk, tvec, W_sc, b_sc, scores);
  k_out<<<1024, 256, 0, stream>>>(scores, gout, target, outp);
}

// Round 13
// 2083.955 us; speedup vs baseline: 1.2190x; 1.1002x over previous
//
#include <hip/hip_runtime.h>

typedef __attribute__((ext_vector_type(8))) short short8v;
typedef __attribute__((ext_vector_type(4))) float f32x4;

#define NB 1024
#define NS 200
#define ND 512
#define NG 1536
#define NM 204800   // NB*NS
#define NFF 256

#define GRU_P 4     // blocks per group (each owns 128 h-cols)
#define GRU_G 64    // groups (each owns 16 batches)

__device__ __forceinline__ float bf2f(unsigned short u){
  union { unsigned u; float f; } v; v.u = ((unsigned)u) << 16; return v.f;
}
__device__ __forceinline__ unsigned short f2bf(float f){
  union { float f; unsigned u; } v; v.f = f;
  unsigned r = v.u + 0x7fffu + ((v.u >> 16) & 1u);
  return (unsigned short)(r >> 16);
}
__device__ __forceinline__ float sigm(float x){ return 1.f / (1.f + __expf(-x)); }
__device__ __forceinline__ float tanhfast(float x){ return 1.f - 2.f / (1.f + __expf(2.f * x)); }

// ---------------- pack W (N x K, row-major, f32) into MFMA B-frag order ----------------
__global__ void k_prepack(const float* __restrict__ W, unsigned short* __restrict__ out,
                          int ld, int coloff, int ntiles){
  int gid = blockIdx.x * 256 + threadIdx.x;
  if (gid >= ntiles * 1024) return;
  int ntile = gid >> 10; int rem = gid & 1023;
  int kk = rem >> 6; int lane = rem & 63;
  int c = ntile * 16 + (lane & 15);
  int k0 = kk * 32 + (lane >> 4) * 8;
  const float* s = W + (size_t)c * ld + coloff + k0;
  uint4 v;
  v.x = (unsigned)f2bf(s[0]) | ((unsigned)f2bf(s[1]) << 16);
  v.y = (unsigned)f2bf(s[2]) | ((unsigned)f2bf(s[3]) << 16);
  v.z = (unsigned)f2bf(s[4]) | ((unsigned)f2bf(s[5]) << 16);
  v.w = (unsigned)f2bf(s[6]) | ((unsigned)f2bf(s[7]) << 16);
  *(uint4*)(out + (size_t)gid * 8) = v;
}

// ---------------- tvec[b][f] = b_fc[f] + sum_d target[b][d] * W_fc[f][512+d] ----------------
__global__ void k_tvec(const float* __restrict__ target, const float* __restrict__ Wfc,
                       const float* __restrict__ bfc, float* __restrict__ tvec){
  __shared__ float tg[4][ND];
  int bb = blockIdx.x;
  int tid = threadIdx.x;
  for (int idx = tid; idx < 4 * ND; idx += 256){
    int j = idx >> 9, d = idx & 511;
    tg[j][d] = target[(size_t)(bb * 4 + j) * ND + d];
  }
  __syncthreads();
  const float* wrow = Wfc + (size_t)tid * 1024 + 512;
  float a0 = 0, a1 = 0, a2 = 0, a3 = 0;
  for (int d = 0; d < ND; ++d){
    float wv = wrow[d];
    a0 += tg[0][d] * wv; a1 += tg[1][d] * wv; a2 += tg[2][d] * wv; a3 += tg[3][d] * wv;
  }
  float bias = bfc[tid];
  tvec[(size_t)(bb * 4 + 0) * NFF + tid] = a0 + bias;
  tvec[(size_t)(bb * 4 + 1) * NFF + tid] = a1 + bias;
  tvec[(size_t)(bb * 4 + 2) * NFF + tid] = a2 + bias;
  tvec[(size_t)(bb * 4 + 3) * NFF + tid] = a3 + bias;
}

// ---------------- gx = history(f32) @ W_ih^T + bias, output bf16 (NM x 1536) ----------------
// bias folds b_ih (all gates) + b_hh (r,z gates; n-gate b_hh multiplies r in the GRU).
__global__ __launch_bounds__(256) void k_gemm_gx(const float* __restrict__ Af,
                                                 const unsigned short* __restrict__ Bpk,
                                                 const float* __restrict__ bih,
                                                 const float* __restrict__ bhh,
                                                 unsigned short* __restrict__ gx){
  __shared__ unsigned short As[128 * 64];
  int tid = threadIdx.x; int lane = tid & 63; int wid = tid >> 6;
  int wm = wid >> 1, wn = wid & 1;
  int Nb = blockIdx.x, Mb = blockIdx.y;
  const float* Abase = Af + (size_t)Mb * 128 * ND;
  const short8v* Bp = (const short8v*)Bpk;
  f32x4 acc[4][4];
  #pragma unroll
  for (int i = 0; i < 4; ++i)
    #pragma unroll
    for (int j = 0; j < 4; ++j) acc[i][j] = (f32x4){0.f, 0.f, 0.f, 0.f};

  for (int kc = 0; kc < 8; ++kc){
    __syncthreads();
    #pragma unroll
    for (int pass = 0; pass < 4; ++pass){
      int idx = pass * 256 + tid; int r = idx >> 3, ch = idx & 7;
      const float* src = Abase + (size_t)r * ND + kc * 64 + ch * 8;
      float4 f0 = *(const float4*)src;
      float4 f1 = *(const float4*)(src + 4);
      uint4 v;
      v.x = (unsigned)f2bf(f0.x) | ((unsigned)f2bf(f0.y) << 16);
      v.y = (unsigned)f2bf(f0.z) | ((unsigned)f2bf(f0.w) << 16);
      v.z = (unsigned)f2bf(f1.x) | ((unsigned)f2bf(f1.y) << 16);
      v.w = (unsigned)f2bf(f1.z) | ((unsigned)f2bf(f1.w) << 16);
      *(uint4*)&As[r * 64 + ch * 8] = v;
    }
    __syncthreads();
    #pragma unroll
    for (int i = 0; i < 2; ++i){
      short8v a[4];
      #pragma unroll
      for (int mt = 0; mt < 4; ++mt)
        a[mt] = *(const short8v*)&As[(wm * 64 + mt * 16 + (lane & 15)) * 64 + i * 32 + (lane >> 4) * 8];
      #pragma unroll
      for (int nt = 0; nt < 4; ++nt){
        short8v b = Bp[((size_t)(Nb * 8 + wn * 4 + nt) * 16 + (kc * 2 + i)) * 64 + lane];
        #pragma unroll
        for (int mt = 0; mt < 4; ++mt)
          acc[mt][nt] = __builtin_amdgcn_mfma_f32_16x16x32_bf16(a[mt], b, acc[mt][nt], 0, 0, 0);
      }
    }
  }
  #pragma unroll
  for (int mt = 0; mt < 4; ++mt){
    #pragma unroll
    for (int nt = 0; nt < 4; ++nt){
      int gcol = Nb * 128 + wn * 64 + nt * 16 + (lane & 15);
      float bv = bih[gcol] + (gcol < 1024 ? bhh[gcol] : 0.f);
      #pragma unroll
      for (int r = 0; r < 4; ++r){
        int grow = Mb * 128 + wm * 64 + mt * 16 + (lane >> 4) * 4 + r;
        gx[(size_t)grow * NG + gcol] = f2bf(acc[mt][nt][r] + bv);
      }
    }
  }
}

// ---------------- GRU recurrence v12 ----------------
// v7 exchange protocol, but 4-wave 256-thread blocks -> 1 wave/SIMD -> 512-reg budget:
// wf[6][16] = 384 regs TRULY resident (v7's 8-wave shape could not physically hold
// 320 regs/wave x 2 waves/SIMD; W_hh was silently re-streamed from L2 every step).
__global__ __launch_bounds__(256, 1) void k_gru12(const unsigned short* __restrict__ gx,
                                                  const unsigned short* __restrict__ Wpk,
                                                  const float* __restrict__ bhh,
                                                  unsigned short* __restrict__ gout,
                                                  unsigned long long* __restrict__ hx,  // [2][1024*128] u64
                                                  int* __restrict__ flags){             // [GRU_G*16] monotonic
  __shared__ unsigned short hbuf[2][16 * 512];   // [parity][16 k-frags of 1KB]
  __shared__ unsigned short hstg[16][136];       // block h-slice transpose staging (+pad)
  int tid = threadIdx.x; int lane = tid & 63; int w = tid >> 6;   // wave 0..3
  int bid = blockIdx.x; int g = bid & 63; int s = bid >> 6;       // group, slice
  int colg = lane & 15;
  int rowg = lane >> 4;
  int c0 = s * 128 + w * 32 + colg;      // sub=0 h-col
  int c1 = c0 + 16;                      // sub=1 h-col
  int b0 = g * 16;                       // group batch base
  int* gfl = flags + g * 16;             // this group's 16 wave-flags

  for (int i = tid; i < 16 * 512; i += 256) hbuf[0][i] = 0;

  // resident W_hh B-fragments: 6 gate tiles x 16 k-frags = 384 regs (1 wave/SIMD)
  short8v wf[6][16];
  const short8v* Wp = (const short8v*)Wpk;
  #pragma unroll
  for (int gg = 0; gg < 3; ++gg)
    #pragma unroll
    for (int j = 0; j < 2; ++j){
      int ntile = gg * 32 + s * 8 + w * 2 + j;
      #pragma unroll
      for (int kk = 0; kk < 16; ++kk)
        wf[gg * 2 + j][kk] = Wp[((size_t)ntile * 16 + kk) * 64 + lane];
    }
  float bN0 = bhh[1024 + c0], bN1 = bhh[1024 + c1];  // r,z biases folded into gx
  float hreg[2][4];
  #pragma unroll
  for (int j = 0; j < 2; ++j)
    #pragma unroll
    for (int r = 0; r < 4; ++r) hreg[j][r] = 0.f;

  // writer mapping: thread -> two u64 (8 cols) of this block's h-slice
  int wbat = tid >> 4;            // 0..15 batch
  int wc2  = (tid & 15) * 2;      // u64 chunk pair within 32

  // preload gx for t=0
  unsigned short cxr[2][4], cxz[2][4], cxn[2][4];
  #pragma unroll
  for (int r = 0; r < 4; ++r){
    const unsigned short* gp = gx + ((size_t)(b0 + rowg * 4 + r) * NS + 0) * NG;
    cxr[0][r] = gp[c0]; cxz[0][r] = gp[512 + c0]; cxn[0][r] = gp[1024 + c0];
    cxr[1][r] = gp[c1]; cxz[1][r] = gp[512 + c1]; cxn[1][r] = gp[1024 + c1];
  }
  __syncthreads();

  #pragma unroll 1
  for (int t = 0; t < NS; ++t){
    int par = t & 1;
    const unsigned short* hr = hbuf[par];
    // gh = h @ Whh_slice^T : 6 gate tiles per wave
    f32x4 acc[6];
    #pragma unroll
    for (int nt = 0; nt < 6; ++nt) acc[nt] = (f32x4){0.f, 0.f, 0.f, 0.f};
    #pragma unroll
    for (int kc = 0; kc < 16; ++kc){
      short8v a = *(const short8v*)&hr[kc * 512 + lane * 8];
      #pragma unroll
      for (int nt = 0; nt < 6; ++nt)
        acc[nt] = __builtin_amdgcn_mfma_f32_16x16x32_bf16(a, wf[nt][kc], acc[nt], 0, 0, 0);
    }
    // activations; h kept f32 in regs
    unsigned short hnew[2][4];
    #pragma unroll
    for (int j = 0; j < 2; ++j){
      float bN = j ? bN1 : bN0;
      #pragma unroll
      for (int r = 0; r < 4; ++r){
        float rr = sigm(bf2f(cxr[j][r]) + acc[j][r]);
        float zz = sigm(bf2f(cxz[j][r]) + acc[2 + j][r]);
        float nn = tanhfast(bf2f(cxn[j][r]) + rr * (acc[4 + j][r] + bN));
        float h = nn + zz * (hreg[j][r] - nn);
        hreg[j][r] = h;
        hnew[j][r] = f2bf(h);
      }
    }

    if (t + 1 < NS){
      unsigned long long* hxp = hx + (size_t)par * (1024 * 128);
      // transpose-stage this block's 16x128 h-slice in LDS
      #pragma unroll
      for (int j = 0; j < 2; ++j)
        #pragma unroll
        for (int r = 0; r < 4; ++r)
          hstg[rowg * 4 + r][w * 32 + j * 16 + colg] = hnew[j][r];
      __syncthreads();   // Bstg: slice staged
      // TWO coalesced 8B coherent stores per thread
      {
        unsigned long long v0 = *(const unsigned long long*)&hstg[wbat][wc2 * 4];
        unsigned long long v1 = *(const unsigned long long*)&hstg[wbat][wc2 * 4 + 4];
        __hip_atomic_store(&hxp[(size_t)(b0 + wbat) * 128 + s * 32 + wc2], v0,
                           __ATOMIC_RELAXED, __HIP_MEMORY_SCOPE_AGENT);
        __hip_atomic_store(&hxp[(size_t)(b0 + wbat) * 128 + s * 32 + wc2 + 1], v1,
                           __ATOMIC_RELAXED, __HIP_MEMORY_SCOPE_AGENT);
      }
      // per-wave drain of the stores, then per-wave flag (publish ASAP)
      asm volatile("s_waitcnt vmcnt(0)" ::: "memory");
      if (lane == 0)
        __hip_atomic_store(&gfl[s * 4 + w], t + 1, __ATOMIC_RELAXED, __HIP_MEMORY_SCOPE_AGENT);
      // off the publish path: gout stores + gx prefetch (fly during poll)
      #pragma unroll
      for (int r = 0; r < 4; ++r){
        unsigned short* gp = gout + ((size_t)(b0 + rowg * 4 + r) * NS + t) * ND;
        gp[c0] = hnew[0][r]; gp[c1] = hnew[1][r];
      }
      #pragma unroll
      for (int r = 0; r < 4; ++r){
        const unsigned short* gp = gx + ((size_t)(b0 + rowg * 4 + r) * NS + (t + 1)) * NG;
        cxr[0][r] = gp[c0]; cxz[0][r] = gp[512 + c0]; cxn[0][r] = gp[1024 + c0];
        cxr[1][r] = gp[c1]; cxz[1][r] = gp[512 + c1]; cxn[1][r] = gp[1024 + c1];
      }
      // all-wave poll of the 16 wave-flags
      {
        int need = t + 1; int fv;
        do {
          fv = (lane < 16) ? __hip_atomic_load(&gfl[lane], __ATOMIC_RELAXED, __HIP_MEMORY_SCOPE_AGENT) : need;
        } while (!__all(fv >= need));
      }
      asm volatile("" ::: "memory");
      // reload full h_t into other-parity LDS in MFMA A-frag layout: wave w -> frags w*4..w*4+3
      unsigned short* hw = hbuf[par ^ 1];
      #pragma unroll
      for (int q = 0; q < 4; ++q){
        int kc = w * 4 + q;
        size_t base = (size_t)(b0 + colg) * 128 + kc * 8 + rowg * 2;
        unsigned long long u0 = __hip_atomic_load(&hxp[base],     __ATOMIC_RELAXED, __HIP_MEMORY_SCOPE_AGENT);
        unsigned long long u1 = __hip_atomic_load(&hxp[base + 1], __ATOMIC_RELAXED, __HIP_MEMORY_SCOPE_AGENT);
        unsigned long long tmp[2] = {u0, u1};
        *(uint4*)&hw[kc * 512 + lane * 8] = *(const uint4*)tmp;
      }
      __syncthreads();   // LDS h ready for next step
    } else {
      #pragma unroll
      for (int r = 0; r < 4; ++r){
        unsigned short* gp = gout + ((size_t)(b0 + rowg * 4 + r) * NS + t) * ND;
        gp[c0] = hnew[0][r]; gp[c1] = hnew[1][r];
      }
    }
  }
}

// ---------------- pre/GELU/scores fused GEMM: (NM x 512) @ Wg^T (256) ----------------
__global__ __launch_bounds__(512) void k_gemm_s4(const unsigned short* __restrict__ A,
                                                 const unsigned short* __restrict__ Bpk,
                                                 const float* __restrict__ tvec,
                                                 const float* __restrict__ Wsc,
                                                 const float* __restrict__ bsc,
                                                 float* __restrict__ scores){
  __shared__ unsigned short As[128 * 64];
  __shared__ float spart[4][128];
  int tid = threadIdx.x; int lane = tid & 63; int wid = tid >> 6;
  int wm = wid >> 2, wn = wid & 3;
  int Mb = blockIdx.x;
  const unsigned short* Abase = A + (size_t)Mb * 128 * ND;
  const short8v* Bp = (const short8v*)Bpk;
  f32x4 acc[4][4];
  #pragma unroll
  for (int i = 0; i < 4; ++i)
    #pragma unroll
    for (int j = 0; j < 4; ++j) acc[i][j] = (f32x4){0.f, 0.f, 0.f, 0.f};

  for (int kc = 0; kc < 8; ++kc){
    __syncthreads();
    #pragma unroll
    for (int pass = 0; pass < 2; ++pass){
      int idx = pass * 512 + tid; int r = idx >> 3, ch = idx & 7;
      uint4 v = *(const uint4*)(Abase + (size_t)r * ND + kc * 64 + ch * 8);
      *(uint4*)&As[r * 64 + ch * 8] = v;
    }
    __syncthreads();
    #pragma unroll
    for (int i = 0; i < 2; ++i){
      short8v a[4];
      #pragma unroll
      for (int mt = 0; mt < 4; ++mt)
        a[mt] = *(const short8v*)&As[(wm * 64 + mt * 16 + (lane & 15)) * 64 + i * 32 + (lane >> 4) * 8];
      #pragma unroll
      for (int nt = 0; nt < 4; ++nt){
        short8v b = Bp[((size_t)(wn * 4 + nt) * 16 + (kc * 2 + i)) * 64 + lane];
        #pragma unroll
        for (int mt = 0; mt < 4; ++mt)
          acc[mt][nt] = __builtin_amdgcn_mfma_f32_16x16x32_bf16(a[mt], b, acc[mt][nt], 0, 0, 0);
      }
    }
  }
  #pragma unroll
  for (int mt = 0; mt < 4; ++mt){
    #pragma unroll
    for (int r = 0; r < 4; ++r){
      int rowl = wm * 64 + mt * 16 + (lane >> 4) * 4 + r;
      unsigned grow = (unsigned)(Mb * 128 + rowl);
      unsigned bidx = grow / 200u;
      float rowsum = 0.f;
      #pragma unroll
      for (int nt = 0; nt < 4; ++nt){
        int gcol = wn * 64 + nt * 16 + (lane & 15);
        float pre = acc[mt][nt][r] + tvec[(size_t)bidx * NFF + gcol];
        float g = 0.5f * pre * (1.f + erff(pre * 0.70710678118654752f));
        rowsum += g * Wsc[gcol];
      }
      rowsum += __shfl_xor(rowsum, 1, 64);
      rowsum += __shfl_xor(rowsum, 2, 64);
      rowsum += __shfl_xor(rowsum, 4, 64);
      rowsum += __shfl_xor(rowsum, 8, 64);
      if ((lane & 15) == 0) spart[wn][rowl] = rowsum;
    }
  }
  __syncthreads();
  if (tid < 128){
    float s = spart[0][tid] + spart[1][tid] + spart[2][tid] + spart[3][tid] + bsc[0];
    scores[(size_t)Mb * 128 + tid] = s;
  }
}

// ---------------- softmax over S + weighted pool + concat output ----------------
__global__ void k_out(const float* __restrict__ scores, const unsigned short* __restrict__ gout,
                      const float* __restrict__ target, float* __restrict__ out){
  int b = blockIdx.x; int tid = threadIdx.x;
  __shared__ float sw[NS];
  __shared__ float red[4];
  float v = (tid < NS) ? scores[(size_t)b * NS + tid] : -3.0e38f;
  float m = v;
  #pragma unroll
  for (int off = 32; off >= 1; off >>= 1) m = fmaxf(m, __shfl_xor(m, off, 64));
  if ((tid & 63) == 0) red[tid >> 6] = m;
  __syncthreads();
  m = fmaxf(fmaxf(red[0], red[1]), fmaxf(red[2], red[3]));
  float e = (tid < NS) ? __expf(v - m) : 0.f;
  if (tid < NS) sw[tid] = e;
  float su = e;
  #pragma unroll
  for (int off = 32; off >= 1; off >>= 1) su += __shfl_xor(su, off, 64);
  __syncthreads();
  if ((tid & 63) == 0) red[tid >> 6] = su;
  __syncthreads();
  float inv = 1.f / (red[0] + red[1] + red[2] + red[3]);
  int d0 = tid * 2;
  float a0 = 0.f, a1 = 0.f;
  const unsigned short* gbase = gout + (size_t)b * NS * ND + d0;
  for (int s = 0; s < NS; ++s){
    unsigned u = *(const unsigned*)(gbase + (size_t)s * ND);
    float wgt = sw[s];
    a0 += wgt * bf2f((unsigned short)(u & 0xffffu));
    a1 += wgt * bf2f((unsigned short)(u >> 16));
  }
  out[(size_t)b * 1024 + d0] = a0 * inv;
  out[(size_t)b * 1024 + d0 + 1] = a1 * inv;
  float2 tv = *(const float2*)(target + (size_t)b * ND + d0);
  out[(size_t)b * 1024 + 512 + d0] = tv.x;
  out[(size_t)b * 1024 + 512 + d0 + 1] = tv.y;
}

extern "C" void kernel_launch(void* const* d_in, const int* in_sizes, int n_in,
                              void* d_out, int out_size, void* d_ws, size_t ws_size,
                              hipStream_t stream) {
  const float* target  = (const float*)d_in[0];
  const float* history = (const float*)d_in[1];
  const float* W_ih    = (const float*)d_in[2];
  const float* W_hh    = (const float*)d_in[3];
  const float* b_ih    = (const float*)d_in[4];
  const float* b_hh    = (const float*)d_in[5];
  const float* W_fc    = (const float*)d_in[6];
  const float* b_fc    = (const float*)d_in[7];
  const float* W_sc    = (const float*)d_in[8];
  const float* b_sc    = (const float*)d_in[9];

  char* ws = (char*)d_ws;
  size_t off = 0;
  unsigned short* gx     = (unsigned short*)(ws + off); off += 629145600ull;  // NM*1536 bf16
  unsigned short* gout   = (unsigned short*)(ws + off); off += 209715200ull;  // NM*512 bf16
  unsigned short* wih_pk = (unsigned short*)(ws + off); off += 1572864ull;
  unsigned short* whh_pk = (unsigned short*)(ws + off); off += 1572864ull;
  unsigned short* wg_pk  = (unsigned short*)(ws + off); off += 262144ull;
  float*          tvec   = (float*)(ws + off);          off += 1048576ull;
  float*          scores = (float*)(ws + off);          off += 819200ull;
  unsigned long long* hx = (unsigned long long*)(ws + off); off += 2097152ull; // [2][1024*128] u64
  int*            flags  = (int*)(ws + off);             off += 4096ull;        // [64*16] monotonic
  if (ws_size < off) return;
  float* outp = (float*)d_out;

  (void)hipMemsetAsync(flags, 0, GRU_G * 16 * sizeof(int), stream);
  k_prepack<<<384, 256, 0, stream>>>(W_ih, wih_pk, 512, 0, 96);
  k_prepack<<<384, 256, 0, stream>>>(W_hh, whh_pk, 512, 0, 96);
  k_prepack<<<64, 256, 0, stream>>>(W_fc, wg_pk, 1024, 0, 16);
  k_tvec<<<256, 256, 0, stream>>>(target, W_fc, b_fc, tvec);
  k_gemm_gx<<<dim3(12, 1600), 256, 0, stream>>>(history, wih_pk, b_ih, b_hh, gx);
  k_gru12<<<256, 256, 0, stream>>>(gx, whh_pk, b_hh, gout, hx, flags);
  k_gemm_s4<<<1600, 512, 0, stream>>>(gout, wg_pk, tvec, W_sc, b_sc, scores);
  k_out<<<1024, 256, 0, stream>>>(scores, gout, target, outp);
}

// Round 14
// 1992.254 us; speedup vs baseline: 1.2751x; 1.0460x over previous
//
#include <hip/hip_runtime.h>

typedef __attribute__((ext_vector_type(8))) short short8v;
typedef __attribute__((ext_vector_type(4))) float f32x4;

#define NB 1024
#define NS 200
#define ND 512
#define NG 1536
#define NM 204800   // NB*NS
#define NFF 256

#define GRU_P 4     // blocks per group (each owns 128 h-cols)
#define GRU_G 64    // groups (each owns 16 batches)

__device__ __forceinline__ float bf2f(unsigned short u){
  union { unsigned u; float f; } v; v.u = ((unsigned)u) << 16; return v.f;
}
__device__ __forceinline__ unsigned short f2bf(float f){
  union { float f; unsigned u; } v; v.f = f;
  unsigned r = v.u + 0x7fffu + ((v.u >> 16) & 1u);
  return (unsigned short)(r >> 16);
}
__device__ __forceinline__ float sigm(float x){ return 1.f / (1.f + __expf(-x)); }
__device__ __forceinline__ float tanhfast(float x){ return 1.f - 2.f / (1.f + __expf(2.f * x)); }

// async global->LDS, 16B per lane; LDS dest = wave-uniform base + lane*16
__device__ __forceinline__ void gld_lds16(const unsigned short* g, unsigned short* l){
  __builtin_amdgcn_global_load_lds(
    (const __attribute__((address_space(1))) unsigned int*)(const void*)g,
    (__attribute__((address_space(3))) unsigned int*)(void*)l, 16, 0, 0);
}

// ---------------- cast f32 -> bf16, 8 elements/thread ----------------
__global__ void k_cast_bf16(const float* __restrict__ in, unsigned short* __restrict__ out, size_t n8){
  size_t i = (size_t)blockIdx.x * blockDim.x + threadIdx.x;
  size_t stride = (size_t)gridDim.x * blockDim.x;
  for (; i < n8; i += stride){
    const float4* p = (const float4*)(in + i * 8);
    float4 a = p[0], b = p[1];
    uint4 v;
    v.x = (unsigned)f2bf(a.x) | ((unsigned)f2bf(a.y) << 16);
    v.y = (unsigned)f2bf(a.z) | ((unsigned)f2bf(a.w) << 16);
    v.z = (unsigned)f2bf(b.x) | ((unsigned)f2bf(b.y) << 16);
    v.w = (unsigned)f2bf(b.z) | ((unsigned)f2bf(b.w) << 16);
    *(uint4*)(out + i * 8) = v;
  }
}

// ---------------- pack W (N x K, row-major, f32) into MFMA B-frag order ----------------
__global__ void k_prepack(const float* __restrict__ W, unsigned short* __restrict__ out,
                          int ld, int coloff, int ntiles){
  int gid = blockIdx.x * 256 + threadIdx.x;
  if (gid >= ntiles * 1024) return;
  int ntile = gid >> 10; int rem = gid & 1023;
  int kk = rem >> 6; int lane = rem & 63;
  int c = ntile * 16 + (lane & 15);
  int k0 = kk * 32 + (lane >> 4) * 8;
  const float* s = W + (size_t)c * ld + coloff + k0;
  uint4 v;
  v.x = (unsigned)f2bf(s[0]) | ((unsigned)f2bf(s[1]) << 16);
  v.y = (unsigned)f2bf(s[2]) | ((unsigned)f2bf(s[3]) << 16);
  v.z = (unsigned)f2bf(s[4]) | ((unsigned)f2bf(s[5]) << 16);
  v.w = (unsigned)f2bf(s[6]) | ((unsigned)f2bf(s[7]) << 16);
  *(uint4*)(out + (size_t)gid * 8) = v;
}

// ---------------- tvec[b][f] = b_fc[f] + sum_d target[b][d] * W_fc[f][512+d] ----------------
__global__ void k_tvec(const float* __restrict__ target, const float* __restrict__ Wfc,
                       const float* __restrict__ bfc, float* __restrict__ tvec){
  __shared__ float tg[4][ND];
  int bb = blockIdx.x;
  int tid = threadIdx.x;
  for (int idx = tid; idx < 4 * ND; idx += 256){
    int j = idx >> 9, d = idx & 511;
    tg[j][d] = target[(size_t)(bb * 4 + j) * ND + d];
  }
  __syncthreads();
  const float* wrow = Wfc + (size_t)tid * 1024 + 512;
  float a0 = 0, a1 = 0, a2 = 0, a3 = 0;
  for (int d = 0; d < ND; ++d){
    float wv = wrow[d];
    a0 += tg[0][d] * wv; a1 += tg[1][d] * wv; a2 += tg[2][d] * wv; a3 += tg[3][d] * wv;
  }
  float bias = bfc[tid];
  tvec[(size_t)(bb * 4 + 0) * NFF + tid] = a0 + bias;
  tvec[(size_t)(bb * 4 + 1) * NFF + tid] = a1 + bias;
  tvec[(size_t)(bb * 4 + 2) * NFF + tid] = a2 + bias;
  tvec[(size_t)(bb * 4 + 3) * NFF + tid] = a3 + bias;
}

// ---------------- gx = histb(bf16) @ W_ih^T + bias, output bf16 (NM x 1536) ----------------
// m97 structure: A staged via global_load_lds (16B/lane, linear LDS), B from packed (L2-hot).
// bias folds b_ih (all gates) + b_hh (r,z gates; n-gate b_hh multiplies r in the GRU).
__global__ __launch_bounds__(256) void k_gemm_gx(const unsigned short* __restrict__ Ab,
                                                 const unsigned short* __restrict__ Bpk,
                                                 const float* __restrict__ bih,
                                                 const float* __restrict__ bhh,
                                                 unsigned short* __restrict__ gx){
  __shared__ unsigned short As[128 * 64];
  int tid = threadIdx.x; int lane = tid & 63; int wid = tid >> 6;
  int wm = wid >> 1, wn = wid & 1;
  int Nb = blockIdx.x, Mb = blockIdx.y;
  const unsigned short* Abase = Ab + (size_t)Mb * 128 * ND;
  const short8v* Bp = (const short8v*)Bpk;
  f32x4 acc[4][4];
  #pragma unroll
  for (int i = 0; i < 4; ++i)
    #pragma unroll
    for (int j = 0; j < 4; ++j) acc[i][j] = (f32x4){0.f, 0.f, 0.f, 0.f};

  for (int kc = 0; kc < 8; ++kc){
    __syncthreads();
    #pragma unroll
    for (int p = 0; p < 4; ++p){
      int idx = p * 256 + tid; int r = idx >> 3, ch = idx & 7;
      const unsigned short* src = Abase + (size_t)r * ND + kc * 64 + ch * 8;
      unsigned short* lb = &As[(size_t)(p * 256 + (tid & ~63)) * 8];   // wave-uniform base
      gld_lds16(src, lb);
    }
    asm volatile("s_waitcnt vmcnt(0)" ::: "memory");
    __syncthreads();
    #pragma unroll
    for (int i = 0; i < 2; ++i){
      short8v a[4];
      #pragma unroll
      for (int mt = 0; mt < 4; ++mt)
        a[mt] = *(const short8v*)&As[(wm * 64 + mt * 16 + (lane & 15)) * 64 + i * 32 + (lane >> 4) * 8];
      #pragma unroll
      for (int nt = 0; nt < 4; ++nt){
        short8v b = Bp[((size_t)(Nb * 8 + wn * 4 + nt) * 16 + (kc * 2 + i)) * 64 + lane];
        #pragma unroll
        for (int mt = 0; mt < 4; ++mt)
          acc[mt][nt] = __builtin_amdgcn_mfma_f32_16x16x32_bf16(a[mt], b, acc[mt][nt], 0, 0, 0);
      }
    }
  }
  #pragma unroll
  for (int mt = 0; mt < 4; ++mt){
    #pragma unroll
    for (int nt = 0; nt < 4; ++nt){
      int gcol = Nb * 128 + wn * 64 + nt * 16 + (lane & 15);
      float bv = bih[gcol] + (gcol < 1024 ? bhh[gcol] : 0.f);
      #pragma unroll
      for (int r = 0; r < 4; ++r){
        int grow = Mb * 128 + wm * 64 + mt * 16 + (lane >> 4) * 4 + r;
        gx[(size_t)grow * NG + gcol] = f2bf(acc[mt][nt][r] + bv);
      }
    }
  }
}

// ---------------- GRU recurrence v12 (UNCHANGED from round 13: best, 1215us) ----------------
__global__ __launch_bounds__(256, 1) void k_gru12(const unsigned short* __restrict__ gx,
                                                  const unsigned short* __restrict__ Wpk,
                                                  const float* __restrict__ bhh,
                                                  unsigned short* __restrict__ gout,
                                                  unsigned long long* __restrict__ hx,  // [2][1024*128] u64
                                                  int* __restrict__ flags){             // [GRU_G*16] monotonic
  __shared__ unsigned short hbuf[2][16 * 512];
  __shared__ unsigned short hstg[16][136];
  int tid = threadIdx.x; int lane = tid & 63; int w = tid >> 6;
  int bid = blockIdx.x; int g = bid & 63; int s = bid >> 6;
  int colg = lane & 15;
  int rowg = lane >> 4;
  int c0 = s * 128 + w * 32 + colg;
  int c1 = c0 + 16;
  int b0 = g * 16;
  int* gfl = flags + g * 16;

  for (int i = tid; i < 16 * 512; i += 256) hbuf[0][i] = 0;

  short8v wf[6][16];
  const short8v* Wp = (const short8v*)Wpk;
  #pragma unroll
  for (int gg = 0; gg < 3; ++gg)
    #pragma unroll
    for (int j = 0; j < 2; ++j){
      int ntile = gg * 32 + s * 8 + w * 2 + j;
      #pragma unroll
      for (int kk = 0; kk < 16; ++kk)
        wf[gg * 2 + j][kk] = Wp[((size_t)ntile * 16 + kk) * 64 + lane];
    }
  float bN0 = bhh[1024 + c0], bN1 = bhh[1024 + c1];
  float hreg[2][4];
  #pragma unroll
  for (int j = 0; j < 2; ++j)
    #pragma unroll
    for (int r = 0; r < 4; ++r) hreg[j][r] = 0.f;

  int wbat = tid >> 4;
  int wc2  = (tid & 15) * 2;

  unsigned short cxr[2][4], cxz[2][4], cxn[2][4];
  #pragma unroll
  for (int r = 0; r < 4; ++r){
    const unsigned short* gp = gx + ((size_t)(b0 + rowg * 4 + r) * NS + 0) * NG;
    cxr[0][r] = gp[c0]; cxz[0][r] = gp[512 + c0]; cxn[0][r] = gp[1024 + c0];
    cxr[1][r] = gp[c1]; cxz[1][r] = gp[512 + c1]; cxn[1][r] = gp[1024 + c1];
  }
  __syncthreads();

  #pragma unroll 1
  for (int t = 0; t < NS; ++t){
    int par = t & 1;
    const unsigned short* hr = hbuf[par];
    f32x4 acc[6];
    #pragma unroll
    for (int nt = 0; nt < 6; ++nt) acc[nt] = (f32x4){0.f, 0.f, 0.f, 0.f};
    #pragma unroll
    for (int kc = 0; kc < 16; ++kc){
      short8v a = *(const short8v*)&hr[kc * 512 + lane * 8];
      #pragma unroll
      for (int nt = 0; nt < 6; ++nt)
        acc[nt] = __builtin_amdgcn_mfma_f32_16x16x32_bf16(a, wf[nt][kc], acc[nt], 0, 0, 0);
    }
    unsigned short hnew[2][4];
    #pragma unroll
    for (int j = 0; j < 2; ++j){
      float bN = j ? bN1 : bN0;
      #pragma unroll
      for (int r = 0; r < 4; ++r){
        float rr = sigm(bf2f(cxr[j][r]) + acc[j][r]);
        float zz = sigm(bf2f(cxz[j][r]) + acc[2 + j][r]);
        float nn = tanhfast(bf2f(cxn[j][r]) + rr * (acc[4 + j][r] + bN));
        float h = nn + zz * (hreg[j][r] - nn);
        hreg[j][r] = h;
        hnew[j][r] = f2bf(h);
      }
    }

    if (t + 1 < NS){
      unsigned long long* hxp = hx + (size_t)par * (1024 * 128);
      #pragma unroll
      for (int j = 0; j < 2; ++j)
        #pragma unroll
        for (int r = 0; r < 4; ++r)
          hstg[rowg * 4 + r][w * 32 + j * 16 + colg] = hnew[j][r];
      __syncthreads();
      {
        unsigned long long v0 = *(const unsigned long long*)&hstg[wbat][wc2 * 4];
        unsigned long long v1 = *(const unsigned long long*)&hstg[wbat][wc2 * 4 + 4];
        __hip_atomic_store(&hxp[(size_t)(b0 + wbat) * 128 + s * 32 + wc2], v0,
                           __ATOMIC_RELAXED, __HIP_MEMORY_SCOPE_AGENT);
        __hip_atomic_store(&hxp[(size_t)(b0 + wbat) * 128 + s * 32 + wc2 + 1], v1,
                           __ATOMIC_RELAXED, __HIP_MEMORY_SCOPE_AGENT);
      }
      asm volatile("s_waitcnt vmcnt(0)" ::: "memory");
      if (lane == 0)
        __hip_atomic_store(&gfl[s * 4 + w], t + 1, __ATOMIC_RELAXED, __HIP_MEMORY_SCOPE_AGENT);
      #pragma unroll
      for (int r = 0; r < 4; ++r){
        unsigned short* gp = gout + ((size_t)(b0 + rowg * 4 + r) * NS + t) * ND;
        gp[c0] = hnew[0][r]; gp[c1] = hnew[1][r];
      }
      #pragma unroll
      for (int r = 0; r < 4; ++r){
        const unsigned short* gp = gx + ((size_t)(b0 + rowg * 4 + r) * NS + (t + 1)) * NG;
        cxr[0][r] = gp[c0]; cxz[0][r] = gp[512 + c0]; cxn[0][r] = gp[1024 + c0];
        cxr[1][r] = gp[c1]; cxz[1][r] = gp[512 + c1]; cxn[1][r] = gp[1024 + c1];
      }
      {
        int need = t + 1; int fv;
        do {
          fv = (lane < 16) ? __hip_atomic_load(&gfl[lane], __ATOMIC_RELAXED, __HIP_MEMORY_SCOPE_AGENT) : need;
        } while (!__all(fv >= need));
      }
      asm volatile("" ::: "memory");
      unsigned short* hw = hbuf[par ^ 1];
      #pragma unroll
      for (int q = 0; q < 4; ++q){
        int kc = w * 4 + q;
        size_t base = (size_t)(b0 + colg) * 128 + kc * 8 + rowg * 2;
        unsigned long long u0 = __hip_atomic_load(&hxp[base],     __ATOMIC_RELAXED, __HIP_MEMORY_SCOPE_AGENT);
        unsigned long long u1 = __hip_atomic_load(&hxp[base + 1], __ATOMIC_RELAXED, __HIP_MEMORY_SCOPE_AGENT);
        unsigned long long tmp[2] = {u0, u1};
        *(uint4*)&hw[kc * 512 + lane * 8] = *(const uint4*)tmp;
      }
      __syncthreads();
    } else {
      #pragma unroll
      for (int r = 0; r < 4; ++r){
        unsigned short* gp = gout + ((size_t)(b0 + rowg * 4 + r) * NS + t) * ND;
        gp[c0] = hnew[0][r]; gp[c1] = hnew[1][r];
      }
    }
  }
}

// ---------------- pre/GELU/scores fused GEMM: (NM x 512) @ Wg^T (256) ----------------
__global__ __launch_bounds__(512) void k_gemm_s4(const unsigned short* __restrict__ A,
                                                 const unsigned short* __restrict__ Bpk,
                                                 const float* __restrict__ tvec,
                                                 const float* __restrict__ Wsc,
                                                 const float* __restrict__ bsc,
                                                 float* __restrict__ scores){
  __shared__ unsigned short As[128 * 64];
  __shared__ float spart[4][128];
  int tid = threadIdx.x; int lane = tid & 63; int wid = tid >> 6;
  int wm = wid >> 2, wn = wid & 3;
  int Mb = blockIdx.x;
  const unsigned short* Abase = A + (size_t)Mb * 128 * ND;
  const short8v* Bp = (const short8v*)Bpk;
  f32x4 acc[4][4];
  #pragma unroll
  for (int i = 0; i < 4; ++i)
    #pragma unroll
    for (int j = 0; j < 4; ++j) acc[i][j] = (f32x4){0.f, 0.f, 0.f, 0.f};

  for (int kc = 0; kc < 8; ++kc){
    __syncthreads();
    #pragma unroll
    for (int pass = 0; pass < 2; ++pass){
      int idx = pass * 512 + tid; int r = idx >> 3, ch = idx & 7;
      uint4 v = *(const uint4*)(Abase + (size_t)r * ND + kc * 64 + ch * 8);
      *(uint4*)&As[r * 64 + ch * 8] = v;
    }
    __syncthreads();
    #pragma unroll
    for (int i = 0; i < 2; ++i){
      short8v a[4];
      #pragma unroll
      for (int mt = 0; mt < 4; ++mt)
        a[mt] = *(const short8v*)&As[(wm * 64 + mt * 16 + (lane & 15)) * 64 + i * 32 + (lane >> 4) * 8];
      #pragma unroll
      for (int nt = 0; nt < 4; ++nt){
        short8v b = Bp[((size_t)(wn * 4 + nt) * 16 + (kc * 2 + i)) * 64 + lane];
        #pragma unroll
        for (int mt = 0; mt < 4; ++mt)
          acc[mt][nt] = __builtin_amdgcn_mfma_f32_16x16x32_bf16(a[mt], b, acc[mt][nt], 0, 0, 0);
      }
    }
  }
  #pragma unroll
  for (int mt = 0; mt < 4; ++mt){
    #pragma unroll
    for (int r = 0; r < 4; ++r){
      int rowl = wm * 64 + mt * 16 + (lane >> 4) * 4 + r;
      unsigned grow = (unsigned)(Mb * 128 + rowl);
      unsigned bidx = grow / 200u;
      float rowsum = 0.f;
      #pragma unroll
      for (int nt = 0; nt < 4; ++nt){
        int gcol = wn * 64 + nt * 16 + (lane & 15);
        float pre = acc[mt][nt][r] + tvec[(size_t)bidx * NFF + gcol];
        // tanh-approx GELU (|err| < ~1e-3, threshold 0.099)
        float p3 = pre * pre * pre;
        float g = 0.5f * pre * (1.f + tanhfast(0.79788456080286536f * (pre + 0.044715f * p3)));
        rowsum += g * Wsc[gcol];
      }
      rowsum += __shfl_xor(rowsum, 1, 64);
      rowsum += __shfl_xor(rowsum, 2, 64);
      rowsum += __shfl_xor(rowsum, 4, 64);
      rowsum += __shfl_xor(rowsum, 8, 64);
      if ((lane & 15) == 0) spart[wn][rowl] = rowsum;
    }
  }
  __syncthreads();
  if (tid < 128){
    float s = spart[0][tid] + spart[1][tid] + spart[2][tid] + spart[3][tid] + bsc[0];
    scores[(size_t)Mb * 128 + tid] = s;
  }
}

// ---------------- softmax over S + weighted pool + concat output ----------------
__global__ void k_out(const float* __restrict__ scores, const unsigned short* __restrict__ gout,
                      const float* __restrict__ target, float* __restrict__ out){
  int b = blockIdx.x; int tid = threadIdx.x;
  __shared__ float sw[NS];
  __shared__ float red[4];
  float v = (tid < NS) ? scores[(size_t)b * NS + tid] : -3.0e38f;
  float m = v;
  #pragma unroll
  for (int off = 32; off >= 1; off >>= 1) m = fmaxf(m, __shfl_xor(m, off, 64));
  if ((tid & 63) == 0) red[tid >> 6] = m;
  __syncthreads();
  m = fmaxf(fmaxf(red[0], red[1]), fmaxf(red[2], red[3]));
  float e = (tid < NS) ? __expf(v - m) : 0.f;
  if (tid < NS) sw[tid] = e;
  float su = e;
  #pragma unroll
  for (int off = 32; off >= 1; off >>= 1) su += __shfl_xor(su, off, 64);
  __syncthreads();
  if ((tid & 63) == 0) red[tid >> 6] = su;
  __syncthreads();
  float inv = 1.f / (red[0] + red[1] + red[2] + red[3]);
  int d0 = tid * 2;
  float a0 = 0.f, a1 = 0.f;
  const unsigned short* gbase = gout + (size_t)b * NS * ND + d0;
  for (int s = 0; s < NS; ++s){
    unsigned u = *(const unsigned*)(gbase + (size_t)s * ND);
    float wgt = sw[s];
    a0 += wgt * bf2f((unsigned short)(u & 0xffffu));
    a1 += wgt * bf2f((unsigned short)(u >> 16));
  }
  out[(size_t)b * 1024 + d0] = a0 * inv;
  out[(size_t)b * 1024 + d0 + 1] = a1 * inv;
  float2 tv = *(const float2*)(target + (size_t)b * ND + d0);
  out[(size_t)b * 1024 + 512 + d0] = tv.x;
  out[(size_t)b * 1024 + 512 + d0 + 1] = tv.y;
}

extern "C" void kernel_launch(void* const* d_in, const int* in_sizes, int n_in,
                              void* d_out, int out_size, void* d_ws, size_t ws_size,
                              hipStream_t stream) {
  const float* target  = (const float*)d_in[0];
  const float* history = (const float*)d_in[1];
  const float* W_ih    = (const float*)d_in[2];
  const float* W_hh    = (const float*)d_in[3];
  const float* b_ih    = (const float*)d_in[4];
  const float* b_hh    = (const float*)d_in[5];
  const float* W_fc    = (const float*)d_in[6];
  const float* b_fc    = (const float*)d_in[7];
  const float* W_sc    = (const float*)d_in[8];
  const float* b_sc    = (const float*)d_in[9];

  char* ws = (char*)d_ws;
  size_t off = 0;
  unsigned short* histb  = (unsigned short*)(ws + off); off += 209715200ull;  // NM*512 bf16
  unsigned short* gx     = (unsigned short*)(ws + off); off += 629145600ull;  // NM*1536 bf16
  unsigned short* gout   = (unsigned short*)(ws + off); off += 209715200ull;  // NM*512 bf16
  unsigned short* wih_pk = (unsigned short*)(ws + off); off += 1572864ull;
  unsigned short* whh_pk = (unsigned short*)(ws + off); off += 1572864ull;
  unsigned short* wg_pk  = (unsigned short*)(ws + off); off += 262144ull;
  float*          tvec   = (float*)(ws + off);          off += 1048576ull;
  float*          scores = (float*)(ws + off);          off += 819200ull;
  unsigned long long* hx = (unsigned long long*)(ws + off); off += 2097152ull; // [2][1024*128] u64
  int*            flags  = (int*)(ws + off);             off += 4096ull;        // [64*16] monotonic
  if (ws_size < off) return;
  float* outp = (float*)d_out;

  (void)hipMemsetAsync(flags, 0, GRU_G * 16 * sizeof(int), stream);
  k_cast_bf16<<<2048, 256, 0, stream>>>(history, histb, (size_t)13107200ull);
  k_prepack<<<384, 256, 0, stream>>>(W_ih, wih_pk, 512, 0, 96);
  k_prepack<<<384, 256, 0, stream>>>(W_hh, whh_pk, 512, 0, 96);
  k_prepack<<<64, 256, 0, stream>>>(W_fc, wg_pk, 1024, 0, 16);
  k_tvec<<<256, 256, 0, stream>>>(target, W_fc, b_fc, tvec);
  k_gemm_gx<<<dim3(12, 1600), 256, 0, stream>>>(histb, wih_pk, b_ih, b_hh, gx);
  k_gru12<<<256, 256, 0, stream>>>(gx, whh_pk, b_hh, gout, hx, flags);
  k_gemm_s4<<<1600, 512, 0, stream>>>(gout, wg_pk, tvec, W_sc, b_sc, scores);
  k_out<<<1024, 256, 0, stream>>>(scores, gout, target, outp);
}

// Round 15
// 1963.474 us; speedup vs baseline: 1.2938x; 1.0147x over previous
//
#include <hip/hip_runtime.h>

typedef __attribute__((ext_vector_type(8))) short short8v;
typedef __attribute__((ext_vector_type(4))) float f32x4;

#define NB 1024
#define NS 200
#define ND 512
#define NG 1536
#define NM 204800   // NB*NS
#define NFF 256

#define GRU_P 4     // blocks per group (each owns 128 h-cols)
#define GRU_G 64    // groups (each owns 16 batches)

__device__ __forceinline__ float bf2f(unsigned short u){
  union { unsigned u; float f; } v; v.u = ((unsigned)u) << 16; return v.f;
}
__device__ __forceinline__ unsigned short f2bf(float f){
  union { float f; unsigned u; } v; v.f = f;
  unsigned r = v.u + 0x7fffu + ((v.u >> 16) & 1u);
  return (unsigned short)(r >> 16);
}
__device__ __forceinline__ float sigm(float x){ return 1.f / (1.f + __expf(-x)); }
__device__ __forceinline__ float tanhfast(float x){ return 1.f - 2.f / (1.f + __expf(2.f * x)); }

// async global->LDS, 16B per lane; LDS dest = wave-uniform base + lane*16
__device__ __forceinline__ void gld_lds16(const unsigned short* g, unsigned short* l){
  __builtin_amdgcn_global_load_lds(
    (const __attribute__((address_space(1))) unsigned int*)(const void*)g,
    (__attribute__((address_space(3))) unsigned int*)(void*)l, 16, 0, 0);
}

// ---------------- cast f32 -> bf16, 8 elements/thread ----------------
__global__ void k_cast_bf16(const float* __restrict__ in, unsigned short* __restrict__ out, size_t n8){
  size_t i = (size_t)blockIdx.x * blockDim.x + threadIdx.x;
  size_t stride = (size_t)gridDim.x * blockDim.x;
  for (; i < n8; i += stride){
    const float4* p = (const float4*)(in + i * 8);
    float4 a = p[0], b = p[1];
    uint4 v;
    v.x = (unsigned)f2bf(a.x) | ((unsigned)f2bf(a.y) << 16);
    v.y = (unsigned)f2bf(a.z) | ((unsigned)f2bf(a.w) << 16);
    v.z = (unsigned)f2bf(b.x) | ((unsigned)f2bf(b.y) << 16);
    v.w = (unsigned)f2bf(b.z) | ((unsigned)f2bf(b.w) << 16);
    *(uint4*)(out + i * 8) = v;
  }
}

// ---------------- pack W (N x K, row-major, f32) into MFMA B-frag order ----------------
__global__ void k_prepack(const float* __restrict__ W, unsigned short* __restrict__ out,
                          int ld, int coloff, int ntiles){
  int gid = blockIdx.x * 256 + threadIdx.x;
  if (gid >= ntiles * 1024) return;
  int ntile = gid >> 10; int rem = gid & 1023;
  int kk = rem >> 6; int lane = rem & 63;
  int c = ntile * 16 + (lane & 15);
  int k0 = kk * 32 + (lane >> 4) * 8;
  const float* s = W + (size_t)c * ld + coloff + k0;
  uint4 v;
  v.x = (unsigned)f2bf(s[0]) | ((unsigned)f2bf(s[1]) << 16);
  v.y = (unsigned)f2bf(s[2]) | ((unsigned)f2bf(s[3]) << 16);
  v.z = (unsigned)f2bf(s[4]) | ((unsigned)f2bf(s[5]) << 16);
  v.w = (unsigned)f2bf(s[6]) | ((unsigned)f2bf(s[7]) << 16);
  *(uint4*)(out + (size_t)gid * 8) = v;
}

// ---------------- tvec[b][f] = b_fc[f] + sum_d target[b][d] * W_fc[f][512+d] ----------------
__global__ void k_tvec(const float* __restrict__ target, const float* __restrict__ Wfc,
                       const float* __restrict__ bfc, float* __restrict__ tvec){
  __shared__ float tg[4][ND];
  int bb = blockIdx.x;
  int tid = threadIdx.x;
  for (int idx = tid; idx < 4 * ND; idx += 256){
    int j = idx >> 9, d = idx & 511;
    tg[j][d] = target[(size_t)(bb * 4 + j) * ND + d];
  }
  __syncthreads();
  const float* wrow = Wfc + (size_t)tid * 1024 + 512;
  float a0 = 0, a1 = 0, a2 = 0, a3 = 0;
  for (int d = 0; d < ND; ++d){
    float wv = wrow[d];
    a0 += tg[0][d] * wv; a1 += tg[1][d] * wv; a2 += tg[2][d] * wv; a3 += tg[3][d] * wv;
  }
  float bias = bfc[tid];
  tvec[(size_t)(bb * 4 + 0) * NFF + tid] = a0 + bias;
  tvec[(size_t)(bb * 4 + 1) * NFF + tid] = a1 + bias;
  tvec[(size_t)(bb * 4 + 2) * NFF + tid] = a2 + bias;
  tvec[(size_t)(bb * 4 + 3) * NFF + tid] = a3 + bias;
}

// ---------------- gx = histb(bf16) @ W_ih^T + bias, output bf16 (NM x 1536) ----------------
// m97 structure + bijective XCD-aware tile swizzle: the 12 blocks sharing an A-panel
// execute on ONE XCD (each XCD owns a contiguous Mb range) -> A fetched once per XCD.
__global__ __launch_bounds__(256) void k_gemm_gx(const unsigned short* __restrict__ Ab,
                                                 const unsigned short* __restrict__ Bpk,
                                                 const float* __restrict__ bih,
                                                 const float* __restrict__ bhh,
                                                 unsigned short* __restrict__ gx){
  __shared__ unsigned short As[128 * 64];
  int tid = threadIdx.x; int lane = tid & 63; int wid = tid >> 6;
  int wm = wid >> 1, wn = wid & 1;
  // XCD swizzle: lin -> tile so XCD c (= lin%8 under round-robin) gets tiles [c*2400,(c+1)*2400)
  int lin = blockIdx.y * 12 + blockIdx.x;           // 0..19199, dispatch-linear
  int tile = (lin & 7) * 2400 + (lin >> 3);         // bijective (19200 % 8 == 0)
  int Mb = tile / 12, Nb = tile % 12;
  const unsigned short* Abase = Ab + (size_t)Mb * 128 * ND;
  const short8v* Bp = (const short8v*)Bpk;
  f32x4 acc[4][4];
  #pragma unroll
  for (int i = 0; i < 4; ++i)
    #pragma unroll
    for (int j = 0; j < 4; ++j) acc[i][j] = (f32x4){0.f, 0.f, 0.f, 0.f};

  for (int kc = 0; kc < 8; ++kc){
    __syncthreads();
    #pragma unroll
    for (int p = 0; p < 4; ++p){
      int idx = p * 256 + tid; int r = idx >> 3, ch = idx & 7;
      const unsigned short* src = Abase + (size_t)r * ND + kc * 64 + ch * 8;
      unsigned short* lb = &As[(size_t)(p * 256 + (tid & ~63)) * 8];   // wave-uniform base
      gld_lds16(src, lb);
    }
    asm volatile("s_waitcnt vmcnt(0)" ::: "memory");
    __syncthreads();
    #pragma unroll
    for (int i = 0; i < 2; ++i){
      short8v a[4];
      #pragma unroll
      for (int mt = 0; mt < 4; ++mt)
        a[mt] = *(const short8v*)&As[(wm * 64 + mt * 16 + (lane & 15)) * 64 + i * 32 + (lane >> 4) * 8];
      #pragma unroll
      for (int nt = 0; nt < 4; ++nt){
        short8v b = Bp[((size_t)(Nb * 8 + wn * 4 + nt) * 16 + (kc * 2 + i)) * 64 + lane];
        #pragma unroll
        for (int mt = 0; mt < 4; ++mt)
          acc[mt][nt] = __builtin_amdgcn_mfma_f32_16x16x32_bf16(a[mt], b, acc[mt][nt], 0, 0, 0);
      }
    }
  }
  #pragma unroll
  for (int mt = 0; mt < 4; ++mt){
    #pragma unroll
    for (int nt = 0; nt < 4; ++nt){
      int gcol = Nb * 128 + wn * 64 + nt * 16 + (lane & 15);
      float bv = bih[gcol] + (gcol < 1024 ? bhh[gcol] : 0.f);
      #pragma unroll
      for (int r = 0; r < 4; ++r){
        int grow = Mb * 128 + wm * 64 + mt * 16 + (lane >> 4) * 4 + r;
        gx[(size_t)grow * NG + gcol] = f2bf(acc[mt][nt][r] + bv);
      }
    }
  }
}

// ---------------- GRU recurrence v12 (UNCHANGED: best, ~1175us) ----------------
__global__ __launch_bounds__(256, 1) void k_gru12(const unsigned short* __restrict__ gx,
                                                  const unsigned short* __restrict__ Wpk,
                                                  const float* __restrict__ bhh,
                                                  unsigned short* __restrict__ gout,
                                                  unsigned long long* __restrict__ hx,  // [2][1024*128] u64
                                                  int* __restrict__ flags){             // [GRU_G*16] monotonic
  __shared__ unsigned short hbuf[2][16 * 512];
  __shared__ unsigned short hstg[16][136];
  int tid = threadIdx.x; int lane = tid & 63; int w = tid >> 6;
  int bid = blockIdx.x; int g = bid & 63; int s = bid >> 6;
  int colg = lane & 15;
  int rowg = lane >> 4;
  int c0 = s * 128 + w * 32 + colg;
  int c1 = c0 + 16;
  int b0 = g * 16;
  int* gfl = flags + g * 16;

  for (int i = tid; i < 16 * 512; i += 256) hbuf[0][i] = 0;

  short8v wf[6][16];
  const short8v* Wp = (const short8v*)Wpk;
  #pragma unroll
  for (int gg = 0; gg < 3; ++gg)
    #pragma unroll
    for (int j = 0; j < 2; ++j){
      int ntile = gg * 32 + s * 8 + w * 2 + j;
      #pragma unroll
      for (int kk = 0; kk < 16; ++kk)
        wf[gg * 2 + j][kk] = Wp[((size_t)ntile * 16 + kk) * 64 + lane];
    }
  float bN0 = bhh[1024 + c0], bN1 = bhh[1024 + c1];
  float hreg[2][4];
  #pragma unroll
  for (int j = 0; j < 2; ++j)
    #pragma unroll
    for (int r = 0; r < 4; ++r) hreg[j][r] = 0.f;

  int wbat = tid >> 4;
  int wc2  = (tid & 15) * 2;

  unsigned short cxr[2][4], cxz[2][4], cxn[2][4];
  #pragma unroll
  for (int r = 0; r < 4; ++r){
    const unsigned short* gp = gx + ((size_t)(b0 + rowg * 4 + r) * NS + 0) * NG;
    cxr[0][r] = gp[c0]; cxz[0][r] = gp[512 + c0]; cxn[0][r] = gp[1024 + c0];
    cxr[1][r] = gp[c1]; cxz[1][r] = gp[512 + c1]; cxn[1][r] = gp[1024 + c1];
  }
  __syncthreads();

  #pragma unroll 1
  for (int t = 0; t < NS; ++t){
    int par = t & 1;
    const unsigned short* hr = hbuf[par];
    f32x4 acc[6];
    #pragma unroll
    for (int nt = 0; nt < 6; ++nt) acc[nt] = (f32x4){0.f, 0.f, 0.f, 0.f};
    #pragma unroll
    for (int kc = 0; kc < 16; ++kc){
      short8v a = *(const short8v*)&hr[kc * 512 + lane * 8];
      #pragma unroll
      for (int nt = 0; nt < 6; ++nt)
        acc[nt] = __builtin_amdgcn_mfma_f32_16x16x32_bf16(a, wf[nt][kc], acc[nt], 0, 0, 0);
    }
    unsigned short hnew[2][4];
    #pragma unroll
    for (int j = 0; j < 2; ++j){
      float bN = j ? bN1 : bN0;
      #pragma unroll
      for (int r = 0; r < 4; ++r){
        float rr = sigm(bf2f(cxr[j][r]) + acc[j][r]);
        float zz = sigm(bf2f(cxz[j][r]) + acc[2 + j][r]);
        float nn = tanhfast(bf2f(cxn[j][r]) + rr * (acc[4 + j][r] + bN));
        float h = nn + zz * (hreg[j][r] - nn);
        hreg[j][r] = h;
        hnew[j][r] = f2bf(h);
      }
    }

    if (t + 1 < NS){
      unsigned long long* hxp = hx + (size_t)par * (1024 * 128);
      #pragma unroll
      for (int j = 0; j < 2; ++j)
        #pragma unroll
        for (int r = 0; r < 4; ++r)
          hstg[rowg * 4 + r][w * 32 + j * 16 + colg] = hnew[j][r];
      __syncthreads();
      {
        unsigned long long v0 = *(const unsigned long long*)&hstg[wbat][wc2 * 4];
        unsigned long long v1 = *(const unsigned long long*)&hstg[wbat][wc2 * 4 + 4];
        __hip_atomic_store(&hxp[(size_t)(b0 + wbat) * 128 + s * 32 + wc2], v0,
                           __ATOMIC_RELAXED, __HIP_MEMORY_SCOPE_AGENT);
        __hip_atomic_store(&hxp[(size_t)(b0 + wbat) * 128 + s * 32 + wc2 + 1], v1,
                           __ATOMIC_RELAXED, __HIP_MEMORY_SCOPE_AGENT);
      }
      asm volatile("s_waitcnt vmcnt(0)" ::: "memory");
      if (lane == 0)
        __hip_atomic_store(&gfl[s * 4 + w], t + 1, __ATOMIC_RELAXED, __HIP_MEMORY_SCOPE_AGENT);
      #pragma unroll
      for (int r = 0; r < 4; ++r){
        unsigned short* gp = gout + ((size_t)(b0 + rowg * 4 + r) * NS + t) * ND;
        gp[c0] = hnew[0][r]; gp[c1] = hnew[1][r];
      }
      #pragma unroll
      for (int r = 0; r < 4; ++r){
        const unsigned short* gp = gx + ((size_t)(b0 + rowg * 4 + r) * NS + (t + 1)) * NG;
        cxr[0][r] = gp[c0]; cxz[0][r] = gp[512 + c0]; cxn[0][r] = gp[1024 + c0];
        cxr[1][r] = gp[c1]; cxz[1][r] = gp[512 + c1]; cxn[1][r] = gp[1024 + c1];
      }
      {
        int need = t + 1; int fv;
        do {
          fv = (lane < 16) ? __hip_atomic_load(&gfl[lane], __ATOMIC_RELAXED, __HIP_MEMORY_SCOPE_AGENT) : need;
        } while (!__all(fv >= need));
      }
      asm volatile("" ::: "memory");
      unsigned short* hw = hbuf[par ^ 1];
      #pragma unroll
      for (int q = 0; q < 4; ++q){
        int kc = w * 4 + q;
        size_t base = (size_t)(b0 + colg) * 128 + kc * 8 + rowg * 2;
        unsigned long long u0 = __hip_atomic_load(&hxp[base],     __ATOMIC_RELAXED, __HIP_MEMORY_SCOPE_AGENT);
        unsigned long long u1 = __hip_atomic_load(&hxp[base + 1], __ATOMIC_RELAXED, __HIP_MEMORY_SCOPE_AGENT);
        unsigned long long tmp[2] = {u0, u1};
        *(uint4*)&hw[kc * 512 + lane * 8] = *(const uint4*)tmp;
      }
      __syncthreads();
    } else {
      #pragma unroll
      for (int r = 0; r < 4; ++r){
        unsigned short* gp = gout + ((size_t)(b0 + rowg * 4 + r) * NS + t) * ND;
        gp[c0] = hnew[0][r]; gp[c1] = hnew[1][r];
      }
    }
  }
}

// ---------------- pre/GELU/scores fused GEMM: (NM x 512) @ Wg^T (256) ----------------
__global__ __launch_bounds__(512) void k_gemm_s4(const unsigned short* __restrict__ A,
                                                 const unsigned short* __restrict__ Bpk,
                                                 const float* __restrict__ tvec,
                                                 const float* __restrict__ Wsc,
                                                 const float* __restrict__ bsc,
                                                 float* __restrict__ scores){
  __shared__ unsigned short As[128 * 64];
  __shared__ float spart[4][128];
  int tid = threadIdx.x; int lane = tid & 63; int wid = tid >> 6;
  int wm = wid >> 2, wn = wid & 3;
  int Mb = blockIdx.x;
  const unsigned short* Abase = A + (size_t)Mb * 128 * ND;
  const short8v* Bp = (const short8v*)Bpk;
  f32x4 acc[4][4];
  #pragma unroll
  for (int i = 0; i < 4; ++i)
    #pragma unroll
    for (int j = 0; j < 4; ++j) acc[i][j] = (f32x4){0.f, 0.f, 0.f, 0.f};

  for (int kc = 0; kc < 8; ++kc){
    __syncthreads();
    #pragma unroll
    for (int pass = 0; pass < 2; ++pass){
      int idx = pass * 512 + tid; int r = idx >> 3, ch = idx & 7;
      const unsigned short* src = Abase + (size_t)r * ND + kc * 64 + ch * 8;
      unsigned short* lb = &As[(size_t)(pass * 512 + (tid & ~63)) * 8];   // wave-uniform base
      gld_lds16(src, lb);
    }
    asm volatile("s_waitcnt vmcnt(0)" ::: "memory");
    __syncthreads();
    #pragma unroll
    for (int i = 0; i < 2; ++i){
      short8v a[4];
      #pragma unroll
      for (int mt = 0; mt < 4; ++mt)
        a[mt] = *(const short8v*)&As[(wm * 64 + mt * 16 + (lane & 15)) * 64 + i * 32 + (lane >> 4) * 8];
      #pragma unroll
      for (int nt = 0; nt < 4; ++nt){
        short8v b = Bp[((size_t)(wn * 4 + nt) * 16 + (kc * 2 + i)) * 64 + lane];
        #pragma unroll
        for (int mt = 0; mt < 4; ++mt)
          acc[mt][nt] = __builtin_amdgcn_mfma_f32_16x16x32_bf16(a[mt], b, acc[mt][nt], 0, 0, 0);
      }
    }
  }
  #pragma unroll
  for (int mt = 0; mt < 4; ++mt){
    #pragma unroll
    for (int r = 0; r < 4; ++r){
      int rowl = wm * 64 + mt * 16 + (lane >> 4) * 4 + r;
      unsigned grow = (unsigned)(Mb * 128 + rowl);
      unsigned bidx = grow / 200u;
      float rowsum = 0.f;
      #pragma unroll
      for (int nt = 0; nt < 4; ++nt){
        int gcol = wn * 64 + nt * 16 + (lane & 15);
        float pre = acc[mt][nt][r] + tvec[(size_t)bidx * NFF + gcol];
        // tanh-approx GELU (|err| < ~1e-3, threshold 0.099)
        float p3 = pre * pre * pre;
        float g = 0.5f * pre * (1.f + tanhfast(0.79788456080286536f * (pre + 0.044715f * p3)));
        rowsum += g * Wsc[gcol];
      }
      rowsum += __shfl_xor(rowsum, 1, 64);
      rowsum += __shfl_xor(rowsum, 2, 64);
      rowsum += __shfl_xor(rowsum, 4, 64);
      rowsum += __shfl_xor(rowsum, 8, 64);
      if ((lane & 15) == 0) spart[wn][rowl] = rowsum;
    }
  }
  __syncthreads();
  if (tid < 128){
    float s = spart[0][tid] + spart[1][tid] + spart[2][tid] + spart[3][tid] + bsc[0];
    scores[(size_t)Mb * 128 + tid] = s;
  }
}

// ---------------- softmax over S + weighted pool + concat output ----------------
__global__ void k_out(const float* __restrict__ scores, const unsigned short* __restrict__ gout,
                      const float* __restrict__ target, float* __restrict__ out){
  int b = blockIdx.x; int tid = threadIdx.x;
  __shared__ float sw[NS];
  __shared__ float red[4];
  float v = (tid < NS) ? scores[(size_t)b * NS + tid] : -3.0e38f;
  float m = v;
  #pragma unroll
  for (int off = 32; off >= 1; off >>= 1) m = fmaxf(m, __shfl_xor(m, off, 64));
  if ((tid & 63) == 0) red[tid >> 6] = m;
  __syncthreads();
  m = fmaxf(fmaxf(red[0], red[1]), fmaxf(red[2], red[3]));
  float e = (tid < NS) ? __expf(v - m) : 0.f;
  if (tid < NS) sw[tid] = e;
  float su = e;
  #pragma unroll
  for (int off = 32; off >= 1; off >>= 1) su += __shfl_xor(su, off, 64);
  __syncthreads();
  if ((tid & 63) == 0) red[tid >> 6] = su;
  __syncthreads();
  float inv = 1.f / (red[0] + red[1] + red[2] + red[3]);
  int d0 = tid * 2;
  float a0 = 0.f, a1 = 0.f;
  const unsigned short* gbase = gout + (size_t)b * NS * ND + d0;
  for (int s = 0; s < NS; ++s){
    unsigned u = *(const unsigned*)(gbase + (size_t)s * ND);
    float wgt = sw[s];
    a0 += wgt * bf2f((unsigned short)(u & 0xffffu));
    a1 += wgt * bf2f((unsigned short)(u >> 16));
  }
  out[(size_t)b * 1024 + d0] = a0 * inv;
  out[(size_t)b * 1024 + d0 + 1] = a1 * inv;
  float2 tv = *(const float2*)(target + (size_t)b * ND + d0);
  out[(size_t)b * 1024 + 512 + d0] = tv.x;
  out[(size_t)b * 1024 + 512 + d0 + 1] = tv.y;
}

extern "C" void kernel_launch(void* const* d_in, const int* in_sizes, int n_in,
                              void* d_out, int out_size, void* d_ws, size_t ws_size,
                              hipStream_t stream) {
  const float* target  = (const float*)d_in[0];
  const float* history = (const float*)d_in[1];
  const float* W_ih    = (const float*)d_in[2];
  const float* W_hh    = (const float*)d_in[3];
  const float* b_ih    = (const float*)d_in[4];
  const float* b_hh    = (const float*)d_in[5];
  const float* W_fc    = (const float*)d_in[6];
  const float* b_fc    = (const float*)d_in[7];
  const float* W_sc    = (const float*)d_in[8];
  const float* b_sc    = (const float*)d_in[9];

  char* ws = (char*)d_ws;
  size_t off = 0;
  unsigned short* histb  = (unsigned short*)(ws + off); off += 209715200ull;  // NM*512 bf16
  unsigned short* gx     = (unsigned short*)(ws + off); off += 629145600ull;  // NM*1536 bf16
  unsigned short* gout   = (unsigned short*)(ws + off); off += 209715200ull;  // NM*512 bf16
  unsigned short* wih_pk = (unsigned short*)(ws + off); off += 1572864ull;
  unsigned short* whh_pk = (unsigned short*)(ws + off); off += 1572864ull;
  unsigned short* wg_pk  = (unsigned short*)(ws + off); off += 262144ull;
  float*          tvec   = (float*)(ws + off);          off += 1048576ull;
  float*          scores = (float*)(ws + off);          off += 819200ull;
  unsigned long long* hx = (unsigned long long*)(ws + off); off += 2097152ull; // [2][1024*128] u64
  int*            flags  = (int*)(ws + off);             off += 4096ull;        // [64*16] monotonic
  if (ws_size < off) return;
  float* outp = (float*)d_out;

  (void)hipMemsetAsync(flags, 0, GRU_G * 16 * sizeof(int), stream);
  k_cast_bf16<<<2048, 256, 0, stream>>>(history, histb, (size_t)13107200ull);
  k_prepack<<<384, 256, 0, stream>>>(W_ih, wih_pk, 512, 0, 96);
  k_prepack<<<384, 256, 0, stream>>>(W_hh, whh_pk, 512, 0, 96);
  k_prepack<<<64, 256, 0, stream>>>(W_fc, wg_pk, 1024, 0, 16);
  k_tvec<<<256, 256, 0, stream>>>(target, W_fc, b_fc, tvec);
  k_gemm_gx<<<dim3(12, 1600), 256, 0, stream>>>(histb, wih_pk, b_ih, b_hh, gx);
  k_gru12<<<256, 256, 0, stream>>>(gx, whh_pk, b_hh, gout, hx, flags);
  k_gemm_s4<<<1600, 512, 0, stream>>>(gout, wg_pk, tvec, W_sc, b_sc, scores);
  k_out<<<1024, 256, 0, stream>>>(scores, gout, target, outp);
}